// Round 12
// baseline (272.687 us; speedup 1.0000x reference)
//
#include <hip/hip_runtime.h>
#include <hip/hip_bf16.h>

typedef unsigned short u16;
typedef __attribute__((ext_vector_type(8))) short bf16x8;
typedef __attribute__((ext_vector_type(4))) float f32x4;
typedef __attribute__((ext_vector_type(16))) float f32x16;
typedef __attribute__((ext_vector_type(4))) unsigned short u16x4;
typedef __attribute__((ext_vector_type(4))) unsigned int u32x4;
typedef __attribute__((ext_vector_type(2))) int i32x2;

__device__ __forceinline__ u16 f2b(float f) {
    __hip_bfloat16 h = __float2bfloat16(f);
    u16 r; __builtin_memcpy(&r, &h, 2); return r;
}
__device__ __forceinline__ float bf2f(u16 u) {
    return __uint_as_float(((unsigned)u) << 16);
}
// async global->LDS, 16B per lane; dest = wave-uniform base + lane*16 (HW)
__device__ __forceinline__ void gload16(const void* g, void* l) {
    __builtin_amdgcn_global_load_lds(
        (const __attribute__((address_space(1))) unsigned int*)g,
        (__attribute__((address_space(3))) unsigned int*)l, 16, 0, 0);
}
// pack 2 f32 -> u32 of 2 bf16 (RNE), single HW instr
__device__ __forceinline__ unsigned cvtpk(float lo, float hi) {
    unsigned d;
    asm("v_cvt_pk_bf16_f32 %0, %1, %2" : "=v"(d) : "v"(lo), "v"(hi));
    return d;
}
// build PV A-fragment (8 bf16) from own 8 P-values via cvt_pk + permlane32_swap.
__device__ __forceinline__ bf16x8 mk_pa(float a0, float a1, float a2, float a3,
                                        float b0, float b1, float b2, float b3) {
    int A0 = (int)cvtpk(a0, a1), A1 = (int)cvtpk(a2, a3);
    int B0 = (int)cvtpk(b0, b1), B1 = (int)cvtpk(b2, b3);
    i32x2 r0 = __builtin_amdgcn_permlane32_swap(A0, B0, false, false);
    i32x2 r1 = __builtin_amdgcn_permlane32_swap(A1, B1, false, false);
    u32x4 fw = { (unsigned)r0[0], (unsigned)r1[0], (unsigned)r0[1], (unsigned)r1[1] };
    return __builtin_bit_cast(bf16x8, fw);
}

// ---------------- fp32 -> bf16 bulk convert (8 elems/thread) --------------------
__global__ __launch_bounds__(256)
void cvt_kernel(const float* __restrict__ in, u16* __restrict__ out) {
    size_t i = ((size_t)blockIdx.x * 256 + threadIdx.x) * 8;
    f32x4 a = *(const f32x4*)(in + i);
    f32x4 b = *(const f32x4*)(in + i + 4);
    u16x4 p0 = { f2b(a[0]), f2b(a[1]), f2b(a[2]), f2b(a[3]) };
    u16x4 p1 = { f2b(b[0]), f2b(b[1]), f2b(b[2]), f2b(b[3]) };
    *(u16x4*)(out + i) = p0;
    *(u16x4*)(out + i + 4) = p1;
}

// ---------------- weight transpose + convert: Wt[n][k] = bf16(W[k][n]) ----------
__global__ __launch_bounds__(256)
void wt_kernel(const float* __restrict__ Wq, const float* __restrict__ Wk,
               const float* __restrict__ Wv, const float* __restrict__ Wo,
               u16* __restrict__ Wt) {
    const float* W = blockIdx.z == 0 ? Wq : blockIdx.z == 1 ? Wk : blockIdx.z == 2 ? Wv : Wo;
    u16* Out = Wt + (size_t)blockIdx.z * (1024 * 1024);
    __shared__ float T[64][65];
    const int t = threadIdx.x;
    const int r0 = blockIdx.y * 64, c0 = blockIdx.x * 64;
#pragma unroll
    for (int e = 0; e < 4; ++e) {
        int row = e * 16 + (t >> 4), c4 = (t & 15) * 4;
        f32x4 v = *(const f32x4*)(W + (r0 + row) * 1024 + c0 + c4);
        T[row][c4] = v[0]; T[row][c4 + 1] = v[1]; T[row][c4 + 2] = v[2]; T[row][c4 + 3] = v[3];
    }
    __syncthreads();
#pragma unroll
    for (int e = 0; e < 4; ++e) {
        int orow = e * 16 + (t >> 4), oc4 = (t & 15) * 4;
        u16x4 pk = { f2b(T[oc4][orow]), f2b(T[oc4 + 1][orow]),
                     f2b(T[oc4 + 2][orow]), f2b(T[oc4 + 3][orow]) };
        *(u16x4*)(Out + (c0 + orow) * 1024 + r0 + oc4) = pk;
    }
}

// ---------------- GEMM (round-7 proven): single-buffer LDS, gload16 DMA ---------
template <int BIAS>
__global__ __launch_bounds__(256)
void gemm_kernel(const u16* __restrict__ Ab, const u16* __restrict__ Bt,
                 u16* __restrict__ Cb, float* __restrict__ Cf,
                 const float* __restrict__ bias) {
    constexpr int K = 1024;
    __shared__ u16 As[128 * 64];
    __shared__ u16 Bs[128 * 64];
    const int tid = threadIdx.x;
    const int lane = tid & 63, w = tid >> 6;
    const int wr = w >> 1, wc = w & 1;
    const int c = lane & 15, g = lane >> 4;
    const int m0 = blockIdx.y * 128, n0 = blockIdx.x * 128;
    const int sr = lane >> 3, sc = (lane & 7) * 8;
    f32x4 acc[4][4] = {};
    for (int kt = 0; kt < 16; ++kt) {
        const int k0 = kt * 64;
#pragma unroll
        for (int i = 0; i < 4; ++i) {
            int row = 32 * w + 8 * i;
            gload16(Ab + (size_t)(m0 + row + sr) * K + k0 + sc, &As[row * 64]);
            gload16(Bt + (size_t)(n0 + row + sr) * K + k0 + sc, &Bs[row * 64]);
        }
        __syncthreads();
#pragma unroll
        for (int kk = 0; kk < 2; ++kk) {
            bf16x8 af[4], bfr[4];
#pragma unroll
            for (int m = 0; m < 4; ++m)
                af[m] = *(const bf16x8*)&As[(wr * 64 + m * 16 + c) * 64 + kk * 32 + 8 * g];
#pragma unroll
            for (int n = 0; n < 4; ++n)
                bfr[n] = *(const bf16x8*)&Bs[(wc * 64 + n * 16 + c) * 64 + kk * 32 + 8 * g];
#pragma unroll
            for (int m = 0; m < 4; ++m)
#pragma unroll
                for (int n = 0; n < 4; ++n)
                    acc[m][n] = __builtin_amdgcn_mfma_f32_16x16x32_bf16(af[m], bfr[n], acc[m][n], 0, 0, 0);
        }
        __syncthreads();
    }
#pragma unroll
    for (int n = 0; n < 4; ++n) {
        int col = n0 + wc * 64 + n * 16 + c;
        float bv = BIAS ? bias[col] : 0.0f;
#pragma unroll
        for (int m = 0; m < 4; ++m) {
            int row0 = m0 + wr * 64 + m * 16 + 4 * g;
#pragma unroll
            for (int r = 0; r < 4; ++r) {
                if (BIAS) Cf[(row0 + r) * 1024 + col] = acc[m][n][r] + bv;
                else      Cb[(row0 + r) * 1024 + col] = f2b(acc[m][n][r]);
            }
        }
    }
}

// ---------------- LayerNorm over D=1024 (bf16 in), write bf16 [bh][s][hd] -------
__global__ __launch_bounds__(256)
void ln_kernel(const u16* __restrict__ P, const float* __restrict__ gamma,
               const float* __restrict__ beta, float mul, u16* __restrict__ Out) {
    const int row = blockIdx.x;
    const int tid = threadIdx.x;
    const int lane = tid & 63, w = tid >> 6;
    u16x4 xr = *(const u16x4*)(P + row * 1024 + tid * 4);
    float x0 = bf2f(xr[0]), x1 = bf2f(xr[1]), x2 = bf2f(xr[2]), x3 = bf2f(xr[3]);
    float s = x0 + x1 + x2 + x3;
    float sq = x0 * x0 + x1 * x1 + x2 * x2 + x3 * x3;
#pragma unroll
    for (int m = 1; m < 64; m <<= 1) { s += __shfl_xor(s, m); sq += __shfl_xor(sq, m); }
    __shared__ float red[8];
    if (lane == 0) { red[w] = s; red[4 + w] = sq; }
    __syncthreads();
    float st = red[0] + red[1] + red[2] + red[3];
    float sqt = red[4] + red[5] + red[6] + red[7];
    float mu = st * (1.0f / 1024.0f);
    float var = sqt * (1.0f / 1024.0f) - mu * mu;
    float rs = rsqrtf(var + 1e-5f);
    f32x4 gm = *(const f32x4*)(gamma + tid * 4);
    f32x4 bt = *(const f32x4*)(beta + tid * 4);
    float xs[4] = {x0, x1, x2, x3};
    u16x4 pk;
#pragma unroll
    for (int j = 0; j < 4; ++j)
        pk[j] = f2b(((xs[j] - mu) * rs * gm[j] + bt[j]) * mul);
    const int b = row >> 11, sI = row & 2047;
    const int col = tid * 4, hh = col >> 6, d = col & 63;
    *(u16x4*)(Out + (((b * 16 + hh) * 2048 + sI) << 6) + d) = pk;
}

// ---------------- V transpose: Vt[bh][64][S] (bf16 in/out) ----------------------
__global__ __launch_bounds__(256)
void vt_kernel(const u16* __restrict__ P, u16* __restrict__ Vt) {
    __shared__ u16 T[64][72];
    const int t = threadIdx.x;
    const int bh = blockIdx.y, s0 = blockIdx.x * 64;
    const int b = bh >> 4, h = bh & 15;
#pragma unroll
    for (int e = 0; e < 4; ++e) {
        int row = e * 16 + (t >> 4), c4 = (t & 15) * 4;
        u16x4 v = *(const u16x4*)(P + (b * 2048 + s0 + row) * 1024 + h * 64 + c4);
        *(u16x4*)&T[row][c4] = v;
    }
    __syncthreads();
#pragma unroll
    for (int e = 0; e < 4; ++e) {
        int dd = e * 16 + (t >> 4), s4 = (t & 15) * 4;
        u16x4 pk = { T[s4][dd], T[s4 + 1][dd], T[s4 + 2][dd], T[s4 + 3][dd] };
        *(u16x4*)(Vt + ((size_t)bh * 64 + dd) * 2048 + s0 + s4) = pk;
    }
}

// ---------------- flash attention v7.1: 32x32 MFMA, in-register P, 4 blocks/CU --
// Identical to v7 except __launch_bounds__(256, 4): 2nd arg is waves/EU, so 3
// capped residency at 3 blocks/CU while the grid supplies 4 (1024/256). LDS
// (4x32KB=128KB) and VGPR (64<=128) both fit 4.
__global__ __launch_bounds__(256, 4)
void attn_kernel(const u16* __restrict__ Qa, const u16* __restrict__ Ka,
                 const u16* __restrict__ Vt, u16* __restrict__ Xa) {
    __shared__ u16 Ks[2][4096];   // 8KB each: [64 k][64 d], row-swizzled
    __shared__ u16 Vs[2][4096];   // 8KB each: [64 d][64 s], row-swizzled
    const int tid = threadIdx.x;
    const int lane = tid & 63, w = tid >> 6;
    const int col = lane & 31, h = lane >> 5;
    const int bid = blockIdx.x;
    const int bh = (bid & 7) * 8 + ((bid >> 3) & 7);
    const int q0 = (bid >> 6) * 128;
    const int b = bh >> 4, hd = bh & 15;
    const int qb = q0 + w * 32;
    const int sw = (col & 7) << 4;   // read-side XOR swizzle (row&7 == col&7)

    // Q fragments (B-operand): qf[s] = Q[qb+col][16s+8h .. +8]
    const u16* qptr = Qa + ((size_t)bh * 2048 + qb + col) * 64;
    bf16x8 qf[4];
#pragma unroll
    for (int s = 0; s < 4; ++s)
        qf[s] = *(const bf16x8*)(qptr + 16 * s + 8 * h);

    // DMA staging geometry (identical to proven v5/v6)
    const int sr = lane >> 3;
    const int scg = ((lane & 7) ^ sr) * 8;
    const u16* kA = Ka + ((size_t)bh * 2048 + sr) * 64 + scg;
    const u16* vA = Vt + ((size_t)bh * 64 + sr) * 2048 + scg;

    f32x16 o0 = {}, o1 = {};
    float li = 0.f;

    // prologue: stage tile 0 into buf 0
#pragma unroll
    for (int j = 0; j < 2; ++j) {
        const int m = 2 * w + j;
        gload16(kA + (size_t)(8 * m) * 64, &Ks[0][8 * m * 64]);
        gload16(vA + (size_t)(8 * m) * 2048, &Vs[0][8 * m * 64]);
    }
    __syncthreads();

    int cur = 0;
    for (int t = 0; t < 32; ++t) {
        const int tn = (t + 1) & 31;
#pragma unroll
        for (int j = 0; j < 2; ++j) {
            const int m = 2 * w + j;
            gload16(kA + (size_t)(tn * 64 + 8 * m) * 64, &Ks[cur ^ 1][8 * m * 64]);
            gload16(vA + (size_t)(8 * m) * 2048 + tn * 64, &Vs[cur ^ 1][8 * m * 64]);
        }

        // QK^T: sacc = S^T blocks, q = qb+col
        const char* kbase = (const char*)&Ks[cur][0];
        f32x16 sacc0 = {}, sacc1 = {};
        __builtin_amdgcn_s_setprio(1);
#pragma unroll
        for (int s = 0; s < 4; ++s) {
            bf16x8 kf0 = *(const bf16x8*)(kbase + (col) * 128       + ((32 * s + 16 * h) ^ sw));
            bf16x8 kf1 = *(const bf16x8*)(kbase + (32 + col) * 128  + ((32 * s + 16 * h) ^ sw));
            sacc0 = __builtin_amdgcn_mfma_f32_32x32x16_bf16(kf0, qf[s], sacc0, 0, 0, 0);
            sacc1 = __builtin_amdgcn_mfma_f32_32x32x16_bf16(kf1, qf[s], sacc1, 0, 0, 0);
        }
        __builtin_amdgcn_s_setprio(0);

        // P = exp2(S) in registers; li accumulates this lane's 32 values
        f32x16 p0, p1;
#pragma unroll
        for (int r = 0; r < 16; ++r) { p0[r] = exp2f(sacc0[r]); }
#pragma unroll
        for (int r = 0; r < 16; ++r) { p1[r] = exp2f(sacc1[r]); }
#pragma unroll
        for (int r = 0; r < 16; ++r) { li += p0[r] + p1[r]; }

        // PV A-fragments fully in-register (cvt_pk + permlane32_swap)
        bf16x8 pa0 = mk_pa(p0[0], p0[1], p0[2], p0[3], p0[4], p0[5], p0[6], p0[7]);
        bf16x8 pa1 = mk_pa(p0[8], p0[9], p0[10], p0[11], p0[12], p0[13], p0[14], p0[15]);
        bf16x8 pa2 = mk_pa(p1[0], p1[1], p1[2], p1[3], p1[4], p1[5], p1[6], p1[7]);
        bf16x8 pa3 = mk_pa(p1[8], p1[9], p1[10], p1[11], p1[12], p1[13], p1[14], p1[15]);

        // PV: o += P-frag x V^T-frag
        const char* vb = (const char*)&Vs[cur][0];
        __builtin_amdgcn_s_setprio(1);
#pragma unroll
        for (int sg = 0; sg < 4; ++sg) {
            bf16x8 pf = sg == 0 ? pa0 : sg == 1 ? pa1 : sg == 2 ? pa2 : pa3;
            const int cb = (32 * sg + 16 * h) ^ sw;
            bf16x8 vf0 = *(const bf16x8*)(vb + (col) * 128      + cb);
            bf16x8 vf1 = *(const bf16x8*)(vb + (32 + col) * 128 + cb);
            o0 = __builtin_amdgcn_mfma_f32_32x32x16_bf16(pf, vf0, o0, 0, 0, 0);
            o1 = __builtin_amdgcn_mfma_f32_32x32x16_bf16(pf, vf1, o1, 0, 0, 0);
        }
        __builtin_amdgcn_s_setprio(0);

        __syncthreads();
        cur ^= 1;
    }

    // li total for q=col (combine lane halves), then per-reg broadcast
    li += __shfl_xor(li, 32);
    float inv = 1.0f / li;
#pragma unroll
    for (int reg = 0; reg < 16; ++reg) {
        const int crow = (reg & 3) + 8 * (reg >> 2) + 4 * h;
        float ivr = __shfl(inv, crow);
        const int row = qb + crow;
        u16* xp = Xa + ((size_t)b * 2048 + row) * 1024 + hd * 64;
        xp[col] = f2b(o0[reg] * ivr);
        xp[32 + col] = f2b(o1[reg] * ivr);
    }
}

// ---------------- launch --------------------------------------------------------
extern "C" void kernel_launch(void* const* d_in, const int* in_sizes, int n_in,
                              void* d_out, int out_size, void* d_ws, size_t ws_size,
                              hipStream_t stream) {
    const float* q   = (const float*)d_in[0];
    const float* k   = (const float*)d_in[1];
    const float* v   = (const float*)d_in[2];
    const float* Wq  = (const float*)d_in[3];
    const float* Wk  = (const float*)d_in[4];
    const float* Wv  = (const float*)d_in[5];
    const float* Wo  = (const float*)d_in[6];
    const float* bo  = (const float*)d_in[7];
    const float* qg  = (const float*)d_in[8];
    const float* qbt = (const float*)d_in[9];
    const float* kg  = (const float*)d_in[10];
    const float* kbt = (const float*)d_in[11];

    char* ws = (char*)d_ws;
    u16* Wt = (u16*)(ws);                    //  8,388,608 B
    u16* Pb = (u16*)(ws + 8388608);          // 16,777,216 B
    u16* Qa = (u16*)(ws + 25165824);         // 16,777,216 B
    u16* Ka = (u16*)(ws + 41943040);         // 16,777,216 B
    u16* Vt = (u16*)(ws + 58720256);         // 16,777,216 B
    u16* Ib = (u16*)(ws + 75497472);         // 16,777,216 B bf16 input slot (end 92MB)
    u16* Xa = Pb;                            // reuse: P dead after vt_kernel

    const float MUL_Q = 0.04508422002778f;   // (1/32) * log2(e)

    wt_kernel<<<dim3(16, 16, 4), 256, 0, stream>>>(Wq, Wk, Wv, Wo, Wt);

    cvt_kernel<<<4096, 256, 0, stream>>>(q, Ib);
    gemm_kernel<0><<<dim3(8, 64), 256, 0, stream>>>(Ib, Wt, Pb, nullptr, nullptr);
    ln_kernel<<<8192, 256, 0, stream>>>(Pb, qg, qbt, MUL_Q, Qa);

    cvt_kernel<<<4096, 256, 0, stream>>>(k, Ib);
    gemm_kernel<0><<<dim3(8, 64), 256, 0, stream>>>(Ib, Wt + 1048576, Pb, nullptr, nullptr);
    ln_kernel<<<8192, 256, 0, stream>>>(Pb, kg, kbt, 1.0f, Ka);

    cvt_kernel<<<4096, 256, 0, stream>>>(v, Ib);
    gemm_kernel<0><<<dim3(8, 64), 256, 0, stream>>>(Ib, Wt + 2097152, Pb, nullptr, nullptr);
    vt_kernel<<<dim3(32, 64), 256, 0, stream>>>(Pb, Vt);

    attn_kernel<<<1024, 256, 0, stream>>>(Qa, Ka, Vt, Xa);

    gemm_kernel<1><<<dim3(8, 64), 256, 0, stream>>>((const u16*)Xa, Wt + 3145728, nullptr, (float*)d_out, bo);
}

// Round 14
// 253.686 us; speedup vs baseline: 1.0749x; 1.0749x over previous
//
#include <hip/hip_runtime.h>
#include <hip/hip_bf16.h>

typedef unsigned short u16;
typedef __attribute__((ext_vector_type(8))) short bf16x8;
typedef __attribute__((ext_vector_type(4))) float f32x4;
typedef __attribute__((ext_vector_type(16))) float f32x16;
typedef __attribute__((ext_vector_type(4))) unsigned short u16x4;
typedef __attribute__((ext_vector_type(4))) unsigned int u32x4;
typedef __attribute__((ext_vector_type(2))) int i32x2;

__device__ __forceinline__ u16 f2b(float f) {
    __hip_bfloat16 h = __float2bfloat16(f);
    u16 r; __builtin_memcpy(&r, &h, 2); return r;
}
__device__ __forceinline__ float bf2f(u16 u) {
    return __uint_as_float(((unsigned)u) << 16);
}
// async global->LDS, 16B per lane; dest = wave-uniform base + lane*16 (HW)
__device__ __forceinline__ void gload16(const void* g, void* l) {
    __builtin_amdgcn_global_load_lds(
        (const __attribute__((address_space(1))) unsigned int*)g,
        (__attribute__((address_space(3))) unsigned int*)l, 16, 0, 0);
}
// native HW exp2 via compiler builtin: single v_exp_f32, compiler-managed
// TRANS-pipe hazard nops (the round-13 inline-asm version hid the opcode from
// the scheduler -> stale-register reads -> absmax 9e-3).
__device__ __forceinline__ float fexp2(float x) {
    return __builtin_amdgcn_exp2f(x);
}
// pack 2 f32 -> u32 of 2 bf16 (RNE), single HW instr
__device__ __forceinline__ unsigned cvtpk(float lo, float hi) {
    unsigned d;
    asm("v_cvt_pk_bf16_f32 %0, %1, %2" : "=v"(d) : "v"(lo), "v"(hi));
    return d;
}
// build PV A-fragment (8 bf16) from own 8 P-values via cvt_pk + permlane32_swap.
__device__ __forceinline__ bf16x8 mk_pa(float a0, float a1, float a2, float a3,
                                        float b0, float b1, float b2, float b3) {
    int A0 = (int)cvtpk(a0, a1), A1 = (int)cvtpk(a2, a3);
    int B0 = (int)cvtpk(b0, b1), B1 = (int)cvtpk(b2, b3);
    i32x2 r0 = __builtin_amdgcn_permlane32_swap(A0, B0, false, false);
    i32x2 r1 = __builtin_amdgcn_permlane32_swap(A1, B1, false, false);
    u32x4 fw = { (unsigned)r0[0], (unsigned)r1[0], (unsigned)r0[1], (unsigned)r1[1] };
    return __builtin_bit_cast(bf16x8, fw);
}

// ---------------- fp32 -> bf16 bulk convert (8 elems/thread) --------------------
__global__ __launch_bounds__(256)
void cvt_kernel(const float* __restrict__ in, u16* __restrict__ out) {
    size_t i = ((size_t)blockIdx.x * 256 + threadIdx.x) * 8;
    f32x4 a = *(const f32x4*)(in + i);
    f32x4 b = *(const f32x4*)(in + i + 4);
    u16x4 p0 = { f2b(a[0]), f2b(a[1]), f2b(a[2]), f2b(a[3]) };
    u16x4 p1 = { f2b(b[0]), f2b(b[1]), f2b(b[2]), f2b(b[3]) };
    *(u16x4*)(out + i) = p0;
    *(u16x4*)(out + i + 4) = p1;
}

// ---------------- weight transpose + convert: Wt[n][k] = bf16(W[k][n]) ----------
__global__ __launch_bounds__(256)
void wt_kernel(const float* __restrict__ Wq, const float* __restrict__ Wk,
               const float* __restrict__ Wv, const float* __restrict__ Wo,
               u16* __restrict__ Wt) {
    const float* W = blockIdx.z == 0 ? Wq : blockIdx.z == 1 ? Wk : blockIdx.z == 2 ? Wv : Wo;
    u16* Out = Wt + (size_t)blockIdx.z * (1024 * 1024);
    __shared__ float T[64][65];
    const int t = threadIdx.x;
    const int r0 = blockIdx.y * 64, c0 = blockIdx.x * 64;
#pragma unroll
    for (int e = 0; e < 4; ++e) {
        int row = e * 16 + (t >> 4), c4 = (t & 15) * 4;
        f32x4 v = *(const f32x4*)(W + (r0 + row) * 1024 + c0 + c4);
        T[row][c4] = v[0]; T[row][c4 + 1] = v[1]; T[row][c4 + 2] = v[2]; T[row][c4 + 3] = v[3];
    }
    __syncthreads();
#pragma unroll
    for (int e = 0; e < 4; ++e) {
        int orow = e * 16 + (t >> 4), oc4 = (t & 15) * 4;
        u16x4 pk = { f2b(T[oc4][orow]), f2b(T[oc4 + 1][orow]),
                     f2b(T[oc4 + 2][orow]), f2b(T[oc4 + 3][orow]) };
        *(u16x4*)(Out + (c0 + orow) * 1024 + r0 + oc4) = pk;
    }
}

// ---------------- GEMM (round-7 proven): single-buffer LDS, gload16 DMA ---------
template <int BIAS>
__global__ __launch_bounds__(256)
void gemm_kernel(const u16* __restrict__ Ab, const u16* __restrict__ Bt,
                 u16* __restrict__ Cb, float* __restrict__ Cf,
                 const float* __restrict__ bias) {
    constexpr int K = 1024;
    __shared__ u16 As[128 * 64];
    __shared__ u16 Bs[128 * 64];
    const int tid = threadIdx.x;
    const int lane = tid & 63, w = tid >> 6;
    const int wr = w >> 1, wc = w & 1;
    const int c = lane & 15, g = lane >> 4;
    const int m0 = blockIdx.y * 128, n0 = blockIdx.x * 128;
    const int sr = lane >> 3, sc = (lane & 7) * 8;
    f32x4 acc[4][4] = {};
    for (int kt = 0; kt < 16; ++kt) {
        const int k0 = kt * 64;
#pragma unroll
        for (int i = 0; i < 4; ++i) {
            int row = 32 * w + 8 * i;
            gload16(Ab + (size_t)(m0 + row + sr) * K + k0 + sc, &As[row * 64]);
            gload16(Bt + (size_t)(n0 + row + sr) * K + k0 + sc, &Bs[row * 64]);
        }
        __syncthreads();
#pragma unroll
        for (int kk = 0; kk < 2; ++kk) {
            bf16x8 af[4], bfr[4];
#pragma unroll
            for (int m = 0; m < 4; ++m)
                af[m] = *(const bf16x8*)&As[(wr * 64 + m * 16 + c) * 64 + kk * 32 + 8 * g];
#pragma unroll
            for (int n = 0; n < 4; ++n)
                bfr[n] = *(const bf16x8*)&Bs[(wc * 64 + n * 16 + c) * 64 + kk * 32 + 8 * g];
#pragma unroll
            for (int m = 0; m < 4; ++m)
#pragma unroll
                for (int n = 0; n < 4; ++n)
                    acc[m][n] = __builtin_amdgcn_mfma_f32_16x16x32_bf16(af[m], bfr[n], acc[m][n], 0, 0, 0);
        }
        __syncthreads();
    }
#pragma unroll
    for (int n = 0; n < 4; ++n) {
        int col = n0 + wc * 64 + n * 16 + c;
        float bv = BIAS ? bias[col] : 0.0f;
#pragma unroll
        for (int m = 0; m < 4; ++m) {
            int row0 = m0 + wr * 64 + m * 16 + 4 * g;
#pragma unroll
            for (int r = 0; r < 4; ++r) {
                if (BIAS) Cf[(row0 + r) * 1024 + col] = acc[m][n][r] + bv;
                else      Cb[(row0 + r) * 1024 + col] = f2b(acc[m][n][r]);
            }
        }
    }
}

// ---------------- LayerNorm over D=1024 (bf16 in), write bf16 [bh][s][hd] -------
__global__ __launch_bounds__(256)
void ln_kernel(const u16* __restrict__ P, const float* __restrict__ gamma,
               const float* __restrict__ beta, float mul, u16* __restrict__ Out) {
    const int row = blockIdx.x;
    const int tid = threadIdx.x;
    const int lane = tid & 63, w = tid >> 6;
    u16x4 xr = *(const u16x4*)(P + row * 1024 + tid * 4);
    float x0 = bf2f(xr[0]), x1 = bf2f(xr[1]), x2 = bf2f(xr[2]), x3 = bf2f(xr[3]);
    float s = x0 + x1 + x2 + x3;
    float sq = x0 * x0 + x1 * x1 + x2 * x2 + x3 * x3;
#pragma unroll
    for (int m = 1; m < 64; m <<= 1) { s += __shfl_xor(s, m); sq += __shfl_xor(sq, m); }
    __shared__ float red[8];
    if (lane == 0) { red[w] = s; red[4 + w] = sq; }
    __syncthreads();
    float st = red[0] + red[1] + red[2] + red[3];
    float sqt = red[4] + red[5] + red[6] + red[7];
    float mu = st * (1.0f / 1024.0f);
    float var = sqt * (1.0f / 1024.0f) - mu * mu;
    float rs = rsqrtf(var + 1e-5f);
    f32x4 gm = *(const f32x4*)(gamma + tid * 4);
    f32x4 bt = *(const f32x4*)(beta + tid * 4);
    float xs[4] = {x0, x1, x2, x3};
    u16x4 pk;
#pragma unroll
    for (int j = 0; j < 4; ++j)
        pk[j] = f2b(((xs[j] - mu) * rs * gm[j] + bt[j]) * mul);
    const int b = row >> 11, sI = row & 2047;
    const int col = tid * 4, hh = col >> 6, d = col & 63;
    *(u16x4*)(Out + (((b * 16 + hh) * 2048 + sI) << 6) + d) = pk;
}

// ---------------- V transpose: Vt[bh][64][S] (bf16 in/out) ----------------------
__global__ __launch_bounds__(256)
void vt_kernel(const u16* __restrict__ P, u16* __restrict__ Vt) {
    __shared__ u16 T[64][72];
    const int t = threadIdx.x;
    const int bh = blockIdx.y, s0 = blockIdx.x * 64;
    const int b = bh >> 4, h = bh & 15;
#pragma unroll
    for (int e = 0; e < 4; ++e) {
        int row = e * 16 + (t >> 4), c4 = (t & 15) * 4;
        u16x4 v = *(const u16x4*)(P + (b * 2048 + s0 + row) * 1024 + h * 64 + c4);
        *(u16x4*)&T[row][c4] = v;
    }
    __syncthreads();
#pragma unroll
    for (int e = 0; e < 4; ++e) {
        int dd = e * 16 + (t >> 4), s4 = (t & 15) * 4;
        u16x4 pk = { T[s4][dd], T[s4 + 1][dd], T[s4 + 2][dd], T[s4 + 3][dd] };
        *(u16x4*)(Vt + ((size_t)bh * 64 + dd) * 2048 + s0 + s4) = pk;
    }
}

// ---------------- flash attention v7.3: builtin exp2 (hazard-safe native) -------
__global__ __launch_bounds__(256, 4)
void attn_kernel(const u16* __restrict__ Qa, const u16* __restrict__ Ka,
                 const u16* __restrict__ Vt, u16* __restrict__ Xa) {
    __shared__ u16 Ks[2][4096];   // 8KB each: [64 k][64 d], row-swizzled
    __shared__ u16 Vs[2][4096];   // 8KB each: [64 d][64 s], row-swizzled
    const int tid = threadIdx.x;
    const int lane = tid & 63, w = tid >> 6;
    const int col = lane & 31, h = lane >> 5;
    const int bid = blockIdx.x;
    const int bh = (bid & 7) * 8 + ((bid >> 3) & 7);
    const int q0 = (bid >> 6) * 128;
    const int b = bh >> 4, hd = bh & 15;
    const int qb = q0 + w * 32;
    const int sw = (col & 7) << 4;   // read-side XOR swizzle (row&7 == col&7)

    // Q fragments (B-operand): qf[s] = Q[qb+col][16s+8h .. +8]
    const u16* qptr = Qa + ((size_t)bh * 2048 + qb + col) * 64;
    bf16x8 qf[4];
#pragma unroll
    for (int s = 0; s < 4; ++s)
        qf[s] = *(const bf16x8*)(qptr + 16 * s + 8 * h);

    // DMA staging geometry (identical to proven v5/v6)
    const int sr = lane >> 3;
    const int scg = ((lane & 7) ^ sr) * 8;
    const u16* kA = Ka + ((size_t)bh * 2048 + sr) * 64 + scg;
    const u16* vA = Vt + ((size_t)bh * 64 + sr) * 2048 + scg;

    f32x16 o0 = {}, o1 = {};
    float li = 0.f;

    // prologue: stage tile 0 into buf 0
#pragma unroll
    for (int j = 0; j < 2; ++j) {
        const int m = 2 * w + j;
        gload16(kA + (size_t)(8 * m) * 64, &Ks[0][8 * m * 64]);
        gload16(vA + (size_t)(8 * m) * 2048, &Vs[0][8 * m * 64]);
    }
    __syncthreads();

    int cur = 0;
    for (int t = 0; t < 32; ++t) {
        const int tn = (t + 1) & 31;
#pragma unroll
        for (int j = 0; j < 2; ++j) {
            const int m = 2 * w + j;
            gload16(kA + (size_t)(tn * 64 + 8 * m) * 64, &Ks[cur ^ 1][8 * m * 64]);
            gload16(vA + (size_t)(8 * m) * 2048 + tn * 64, &Vs[cur ^ 1][8 * m * 64]);
        }

        // QK^T: sacc = S^T blocks, q = qb+col
        const char* kbase = (const char*)&Ks[cur][0];
        f32x16 sacc0 = {}, sacc1 = {};
        __builtin_amdgcn_s_setprio(1);
#pragma unroll
        for (int s = 0; s < 4; ++s) {
            bf16x8 kf0 = *(const bf16x8*)(kbase + (col) * 128       + ((32 * s + 16 * h) ^ sw));
            bf16x8 kf1 = *(const bf16x8*)(kbase + (32 + col) * 128  + ((32 * s + 16 * h) ^ sw));
            sacc0 = __builtin_amdgcn_mfma_f32_32x32x16_bf16(kf0, qf[s], sacc0, 0, 0, 0);
            sacc1 = __builtin_amdgcn_mfma_f32_32x32x16_bf16(kf1, qf[s], sacc1, 0, 0, 0);
        }
        __builtin_amdgcn_s_setprio(0);

        // P = exp2(S) via native v_exp_f32 (builtin); li sums this lane's 32
        f32x16 p0, p1;
#pragma unroll
        for (int r = 0; r < 16; ++r) { p0[r] = fexp2(sacc0[r]); }
#pragma unroll
        for (int r = 0; r < 16; ++r) { p1[r] = fexp2(sacc1[r]); }
#pragma unroll
        for (int r = 0; r < 16; ++r) { li += p0[r] + p1[r]; }

        // PV A-fragments fully in-register (cvt_pk + permlane32_swap)
        bf16x8 pa0 = mk_pa(p0[0], p0[1], p0[2], p0[3], p0[4], p0[5], p0[6], p0[7]);
        bf16x8 pa1 = mk_pa(p0[8], p0[9], p0[10], p0[11], p0[12], p0[13], p0[14], p0[15]);
        bf16x8 pa2 = mk_pa(p1[0], p1[1], p1[2], p1[3], p1[4], p1[5], p1[6], p1[7]);
        bf16x8 pa3 = mk_pa(p1[8], p1[9], p1[10], p1[11], p1[12], p1[13], p1[14], p1[15]);

        // PV: o += P-frag x V^T-frag
        const char* vb = (const char*)&Vs[cur][0];
        __builtin_amdgcn_s_setprio(1);
#pragma unroll
        for (int sg = 0; sg < 4; ++sg) {
            bf16x8 pf = sg == 0 ? pa0 : sg == 1 ? pa1 : sg == 2 ? pa2 : pa3;
            const int cb = (32 * sg + 16 * h) ^ sw;
            bf16x8 vf0 = *(const bf16x8*)(vb + (col) * 128      + cb);
            bf16x8 vf1 = *(const bf16x8*)(vb + (32 + col) * 128 + cb);
            o0 = __builtin_amdgcn_mfma_f32_32x32x16_bf16(pf, vf0, o0, 0, 0, 0);
            o1 = __builtin_amdgcn_mfma_f32_32x32x16_bf16(pf, vf1, o1, 0, 0, 0);
        }
        __builtin_amdgcn_s_setprio(0);

        __syncthreads();
        cur ^= 1;
    }

    // li total for q=col (combine lane halves), then per-reg broadcast
    li += __shfl_xor(li, 32);
    float inv = 1.0f / li;
#pragma unroll
    for (int reg = 0; reg < 16; ++reg) {
        const int crow = (reg & 3) + 8 * (reg >> 2) + 4 * h;
        float ivr = __shfl(inv, crow);
        const int row = qb + crow;
        u16* xp = Xa + ((size_t)b * 2048 + row) * 1024 + hd * 64;
        xp[col] = f2b(o0[reg] * ivr);
        xp[32 + col] = f2b(o1[reg] * ivr);
    }
}

// ---------------- launch --------------------------------------------------------
extern "C" void kernel_launch(void* const* d_in, const int* in_sizes, int n_in,
                              void* d_out, int out_size, void* d_ws, size_t ws_size,
                              hipStream_t stream) {
    const float* q   = (const float*)d_in[0];
    const float* k   = (const float*)d_in[1];
    const float* v   = (const float*)d_in[2];
    const float* Wq  = (const float*)d_in[3];
    const float* Wk  = (const float*)d_in[4];
    const float* Wv  = (const float*)d_in[5];
    const float* Wo  = (const float*)d_in[6];
    const float* bo  = (const float*)d_in[7];
    const float* qg  = (const float*)d_in[8];
    const float* qbt = (const float*)d_in[9];
    const float* kg  = (const float*)d_in[10];
    const float* kbt = (const float*)d_in[11];

    char* ws = (char*)d_ws;
    u16* Wt = (u16*)(ws);                    //  8,388,608 B
    u16* Pb = (u16*)(ws + 8388608);          // 16,777,216 B
    u16* Qa = (u16*)(ws + 25165824);         // 16,777,216 B
    u16* Ka = (u16*)(ws + 41943040);         // 16,777,216 B
    u16* Vt = (u16*)(ws + 58720256);         // 16,777,216 B
    u16* Ib = (u16*)(ws + 75497472);         // 16,777,216 B bf16 input slot (end 92MB)
    u16* Xa = Pb;                            // reuse: P dead after vt_kernel

    const float MUL_Q = 0.04508422002778f;   // (1/32) * log2(e)

    wt_kernel<<<dim3(16, 16, 4), 256, 0, stream>>>(Wq, Wk, Wv, Wo, Wt);

    cvt_kernel<<<4096, 256, 0, stream>>>(q, Ib);
    gemm_kernel<0><<<dim3(8, 64), 256, 0, stream>>>(Ib, Wt, Pb, nullptr, nullptr);
    ln_kernel<<<8192, 256, 0, stream>>>(Pb, qg, qbt, MUL_Q, Qa);

    cvt_kernel<<<4096, 256, 0, stream>>>(k, Ib);
    gemm_kernel<0><<<dim3(8, 64), 256, 0, stream>>>(Ib, Wt + 1048576, Pb, nullptr, nullptr);
    ln_kernel<<<8192, 256, 0, stream>>>(Pb, kg, kbt, 1.0f, Ka);

    cvt_kernel<<<4096, 256, 0, stream>>>(v, Ib);
    gemm_kernel<0><<<dim3(8, 64), 256, 0, stream>>>(Ib, Wt + 2097152, Pb, nullptr, nullptr);
    vt_kernel<<<dim3(32, 64), 256, 0, stream>>>(Pb, Vt);

    attn_kernel<<<1024, 256, 0, stream>>>(Qa, Ka, Vt, Xa);

    gemm_kernel<1><<<dim3(8, 64), 256, 0, stream>>>((const u16*)Xa, Wt + 3145728, nullptr, (float*)d_out, bo);
}

// Round 15
// 242.243 us; speedup vs baseline: 1.1257x; 1.0472x over previous
//
#include <hip/hip_runtime.h>
#include <hip/hip_bf16.h>

typedef unsigned short u16;
typedef __attribute__((ext_vector_type(8))) short bf16x8;
typedef __attribute__((ext_vector_type(4))) float f32x4;
typedef __attribute__((ext_vector_type(16))) float f32x16;
typedef __attribute__((ext_vector_type(4))) unsigned short u16x4;
typedef __attribute__((ext_vector_type(4))) unsigned int u32x4;
typedef __attribute__((ext_vector_type(2))) int i32x2;

__device__ __forceinline__ u16 f2b(float f) {
    __hip_bfloat16 h = __float2bfloat16(f);
    u16 r; __builtin_memcpy(&r, &h, 2); return r;
}
__device__ __forceinline__ float bf2f(u16 u) {
    return __uint_as_float(((unsigned)u) << 16);
}
__device__ __forceinline__ void gload16(const void* g, void* l) {
    __builtin_amdgcn_global_load_lds(
        (const __attribute__((address_space(1))) unsigned int*)g,
        (__attribute__((address_space(3))) unsigned int*)l, 16, 0, 0);
}
// native HW exp2 via builtin (compiler-managed TRANS hazards; r13 lesson)
__device__ __forceinline__ float fexp2(float x) {
    return __builtin_amdgcn_exp2f(x);
}
__device__ __forceinline__ unsigned cvtpk(float lo, float hi) {
    unsigned d;
    asm("v_cvt_pk_bf16_f32 %0, %1, %2" : "=v"(d) : "v"(lo), "v"(hi));
    return d;
}
__device__ __forceinline__ bf16x8 mk_pa(float a0, float a1, float a2, float a3,
                                        float b0, float b1, float b2, float b3) {
    int A0 = (int)cvtpk(a0, a1), A1 = (int)cvtpk(a2, a3);
    int B0 = (int)cvtpk(b0, b1), B1 = (int)cvtpk(b2, b3);
    i32x2 r0 = __builtin_amdgcn_permlane32_swap(A0, B0, false, false);
    i32x2 r1 = __builtin_amdgcn_permlane32_swap(A1, B1, false, false);
    u32x4 fw = { (unsigned)r0[0], (unsigned)r1[0], (unsigned)r0[1], (unsigned)r1[1] };
    return __builtin_bit_cast(bf16x8, fw);
}

// ---------------- fp32 -> bf16 bulk convert (8 elems/thread) --------------------
__global__ __launch_bounds__(256)
void cvt_kernel(const float* __restrict__ in, u16* __restrict__ out) {
    size_t i = ((size_t)blockIdx.x * 256 + threadIdx.x) * 8;
    f32x4 a = *(const f32x4*)(in + i);
    f32x4 b = *(const f32x4*)(in + i + 4);
    u16x4 p0 = { f2b(a[0]), f2b(a[1]), f2b(a[2]), f2b(a[3]) };
    u16x4 p1 = { f2b(b[0]), f2b(b[1]), f2b(b[2]), f2b(b[3]) };
    *(u16x4*)(out + i) = p0;
    *(u16x4*)(out + i + 4) = p1;
}

// z=3 batched convert: q/k/v -> Ib3 slots
__global__ __launch_bounds__(256)
void cvt3_kernel(const float* __restrict__ q, const float* __restrict__ k,
                 const float* __restrict__ v, u16* __restrict__ out3) {
    const int z = blockIdx.z;
    const float* in = z == 0 ? q : z == 1 ? k : v;
    u16* out = out3 + (size_t)z * 8388608;
    size_t i = ((size_t)blockIdx.x * 256 + threadIdx.x) * 8;
    f32x4 a = *(const f32x4*)(in + i);
    f32x4 b = *(const f32x4*)(in + i + 4);
    u16x4 p0 = { f2b(a[0]), f2b(a[1]), f2b(a[2]), f2b(a[3]) };
    u16x4 p1 = { f2b(b[0]), f2b(b[1]), f2b(b[2]), f2b(b[3]) };
    *(u16x4*)(out + i) = p0;
    *(u16x4*)(out + i + 4) = p1;
}

// ---------------- weight transpose + convert: Wt[n][k] = bf16(W[k][n]) ----------
__global__ __launch_bounds__(256)
void wt_kernel(const float* __restrict__ Wq, const float* __restrict__ Wk,
               const float* __restrict__ Wv, const float* __restrict__ Wo,
               u16* __restrict__ Wt) {
    const float* W = blockIdx.z == 0 ? Wq : blockIdx.z == 1 ? Wk : blockIdx.z == 2 ? Wv : Wo;
    u16* Out = Wt + (size_t)blockIdx.z * (1024 * 1024);
    __shared__ float T[64][65];
    const int t = threadIdx.x;
    const int r0 = blockIdx.y * 64, c0 = blockIdx.x * 64;
#pragma unroll
    for (int e = 0; e < 4; ++e) {
        int row = e * 16 + (t >> 4), c4 = (t & 15) * 4;
        f32x4 v = *(const f32x4*)(W + (r0 + row) * 1024 + c0 + c4);
        T[row][c4] = v[0]; T[row][c4 + 1] = v[1]; T[row][c4 + 2] = v[2]; T[row][c4 + 3] = v[3];
    }
    __syncthreads();
#pragma unroll
    for (int e = 0; e < 4; ++e) {
        int orow = e * 16 + (t >> 4), oc4 = (t & 15) * 4;
        u16x4 pk = { f2b(T[oc4][orow]), f2b(T[oc4 + 1][orow]),
                     f2b(T[oc4 + 2][orow]), f2b(T[oc4 + 3][orow]) };
        *(u16x4*)(Out + (c0 + orow) * 1024 + r0 + oc4) = pk;
    }
}

// ---------------- GEMM core (round-7 proven): single-buffer LDS, gload16 DMA ----
template <int BIAS>
__device__ __forceinline__ void gemm_body(const u16* __restrict__ Ab,
                                          const u16* __restrict__ Bt,
                                          u16* __restrict__ Cb, float* __restrict__ Cf,
                                          const float* __restrict__ bias,
                                          u16* As, u16* Bs, int bx, int by) {
    constexpr int K = 1024;
    const int tid = threadIdx.x;
    const int lane = tid & 63, w = tid >> 6;
    const int wr = w >> 1, wc = w & 1;
    const int c = lane & 15, g = lane >> 4;
    const int m0 = by * 128, n0 = bx * 128;
    const int sr = lane >> 3, sc = (lane & 7) * 8;
    f32x4 acc[4][4] = {};
    for (int kt = 0; kt < 16; ++kt) {
        const int k0 = kt * 64;
#pragma unroll
        for (int i = 0; i < 4; ++i) {
            int row = 32 * w + 8 * i;
            gload16(Ab + (size_t)(m0 + row + sr) * K + k0 + sc, &As[row * 64]);
            gload16(Bt + (size_t)(n0 + row + sr) * K + k0 + sc, &Bs[row * 64]);
        }
        __syncthreads();
#pragma unroll
        for (int kk = 0; kk < 2; ++kk) {
            bf16x8 af[4], bfr[4];
#pragma unroll
            for (int m = 0; m < 4; ++m)
                af[m] = *(const bf16x8*)&As[(wr * 64 + m * 16 + c) * 64 + kk * 32 + 8 * g];
#pragma unroll
            for (int n = 0; n < 4; ++n)
                bfr[n] = *(const bf16x8*)&Bs[(wc * 64 + n * 16 + c) * 64 + kk * 32 + 8 * g];
#pragma unroll
            for (int m = 0; m < 4; ++m)
#pragma unroll
                for (int n = 0; n < 4; ++n)
                    acc[m][n] = __builtin_amdgcn_mfma_f32_16x16x32_bf16(af[m], bfr[n], acc[m][n], 0, 0, 0);
        }
        __syncthreads();
    }
#pragma unroll
    for (int n = 0; n < 4; ++n) {
        int col = n0 + wc * 64 + n * 16 + c;
        float bv = BIAS ? bias[col] : 0.0f;
#pragma unroll
        for (int m = 0; m < 4; ++m) {
            int row0 = m0 + wr * 64 + m * 16 + 4 * g;
#pragma unroll
            for (int r = 0; r < 4; ++r) {
                if (BIAS) Cf[(row0 + r) * 1024 + col] = acc[m][n][r] + bv;
                else      Cb[(row0 + r) * 1024 + col] = f2b(acc[m][n][r]);
            }
        }
    }
}

template <int BIAS>
__global__ __launch_bounds__(256)
void gemm_kernel(const u16* __restrict__ Ab, const u16* __restrict__ Bt,
                 u16* __restrict__ Cb, float* __restrict__ Cf,
                 const float* __restrict__ bias) {
    __shared__ u16 As[128 * 64];
    __shared__ u16 Bs[128 * 64];
    gemm_body<BIAS>(Ab, Bt, Cb, Cf, bias, As, Bs, blockIdx.x, blockIdx.y);
}

// z=3 batched projection GEMM: 1536 blocks -> ~5 blocks/CU resident (vs 2),
// hides the vmcnt(0)+barrier drain with inter-block TLP.
__global__ __launch_bounds__(256)
void gemm3_kernel(const u16* __restrict__ A3, const u16* __restrict__ Wt,
                  u16* __restrict__ C3) {
    __shared__ u16 As[128 * 64];
    __shared__ u16 Bs[128 * 64];
    const int z = blockIdx.z;
    gemm_body<0>(A3 + (size_t)z * 8388608, Wt + (size_t)z * 1048576,
                 C3 + (size_t)z * 8388608, nullptr, nullptr, As, Bs,
                 blockIdx.x, blockIdx.y);
}

// ---------------- LayerNorm over D=1024 (bf16 in), write bf16 [bh][s][hd] -------
__device__ __forceinline__ void ln_body(const u16* __restrict__ P,
                                        const float* __restrict__ gamma,
                                        const float* __restrict__ beta,
                                        float mul, u16* __restrict__ Out) {
    const int row = blockIdx.x;
    const int tid = threadIdx.x;
    const int lane = tid & 63, w = tid >> 6;
    u16x4 xr = *(const u16x4*)(P + row * 1024 + tid * 4);
    float x0 = bf2f(xr[0]), x1 = bf2f(xr[1]), x2 = bf2f(xr[2]), x3 = bf2f(xr[3]);
    float s = x0 + x1 + x2 + x3;
    float sq = x0 * x0 + x1 * x1 + x2 * x2 + x3 * x3;
#pragma unroll
    for (int m = 1; m < 64; m <<= 1) { s += __shfl_xor(s, m); sq += __shfl_xor(sq, m); }
    __shared__ float red[8];
    if (lane == 0) { red[w] = s; red[4 + w] = sq; }
    __syncthreads();
    float st = red[0] + red[1] + red[2] + red[3];
    float sqt = red[4] + red[5] + red[6] + red[7];
    float mu = st * (1.0f / 1024.0f);
    float var = sqt * (1.0f / 1024.0f) - mu * mu;
    float rs = rsqrtf(var + 1e-5f);
    f32x4 gm = *(const f32x4*)(gamma + tid * 4);
    f32x4 bt = *(const f32x4*)(beta + tid * 4);
    float xs[4] = {x0, x1, x2, x3};
    u16x4 pk;
#pragma unroll
    for (int j = 0; j < 4; ++j)
        pk[j] = f2b(((xs[j] - mu) * rs * gm[j] + bt[j]) * mul);
    const int b = row >> 11, sI = row & 2047;
    const int col = tid * 4, hh = col >> 6, d = col & 63;
    *(u16x4*)(Out + (((b * 16 + hh) * 2048 + sI) << 6) + d) = pk;
}

__global__ __launch_bounds__(256)
void ln_kernel(const u16* __restrict__ P, const float* __restrict__ gamma,
               const float* __restrict__ beta, float mul, u16* __restrict__ Out) {
    ln_body(P, gamma, beta, mul, Out);
}

// z=2 batched LN: z=0 -> q (MUL_Q), z=1 -> k (1.0)
__global__ __launch_bounds__(256)
void ln2_kernel(const u16* __restrict__ P3,
                const float* __restrict__ qg, const float* __restrict__ qb,
                const float* __restrict__ kg, const float* __restrict__ kb,
                u16* __restrict__ Qa, u16* __restrict__ Ka, float mulq) {
    const int z = blockIdx.z;
    ln_body(P3 + (size_t)z * 8388608, z == 0 ? qg : kg, z == 0 ? qb : kb,
            z == 0 ? mulq : 1.0f, z == 0 ? Qa : Ka);
}

// ---------------- V transpose: Vt[bh][64][S] (bf16 in/out) ----------------------
__global__ __launch_bounds__(256)
void vt_kernel(const u16* __restrict__ P, u16* __restrict__ Vt) {
    __shared__ u16 T[64][72];
    const int t = threadIdx.x;
    const int bh = blockIdx.y, s0 = blockIdx.x * 64;
    const int b = bh >> 4, h = bh & 15;
#pragma unroll
    for (int e = 0; e < 4; ++e) {
        int row = e * 16 + (t >> 4), c4 = (t & 15) * 4;
        u16x4 v = *(const u16x4*)(P + (b * 2048 + s0 + row) * 1024 + h * 64 + c4);
        *(u16x4*)&T[row][c4] = v;
    }
    __syncthreads();
#pragma unroll
    for (int e = 0; e < 4; ++e) {
        int dd = e * 16 + (t >> 4), s4 = (t & 15) * 4;
        u16x4 pk = { T[s4][dd], T[s4 + 1][dd], T[s4 + 2][dd], T[s4 + 3][dd] };
        *(u16x4*)(Vt + ((size_t)bh * 64 + dd) * 2048 + s0 + s4) = pk;
    }
}

// ---------------- flash attention v7.3 (round-14 exact) -------------------------
__global__ __launch_bounds__(256, 4)
void attn_kernel(const u16* __restrict__ Qa, const u16* __restrict__ Ka,
                 const u16* __restrict__ Vt, u16* __restrict__ Xa) {
    __shared__ u16 Ks[2][4096];
    __shared__ u16 Vs[2][4096];
    const int tid = threadIdx.x;
    const int lane = tid & 63, w = tid >> 6;
    const int col = lane & 31, h = lane >> 5;
    const int bid = blockIdx.x;
    const int bh = (bid & 7) * 8 + ((bid >> 3) & 7);
    const int q0 = (bid >> 6) * 128;
    const int b = bh >> 4, hd = bh & 15;
    const int qb = q0 + w * 32;
    const int sw = (col & 7) << 4;

    const u16* qptr = Qa + ((size_t)bh * 2048 + qb + col) * 64;
    bf16x8 qf[4];
#pragma unroll
    for (int s = 0; s < 4; ++s)
        qf[s] = *(const bf16x8*)(qptr + 16 * s + 8 * h);

    const int sr = lane >> 3;
    const int scg = ((lane & 7) ^ sr) * 8;
    const u16* kA = Ka + ((size_t)bh * 2048 + sr) * 64 + scg;
    const u16* vA = Vt + ((size_t)bh * 64 + sr) * 2048 + scg;

    f32x16 o0 = {}, o1 = {};
    float li = 0.f;

#pragma unroll
    for (int j = 0; j < 2; ++j) {
        const int m = 2 * w + j;
        gload16(kA + (size_t)(8 * m) * 64, &Ks[0][8 * m * 64]);
        gload16(vA + (size_t)(8 * m) * 2048, &Vs[0][8 * m * 64]);
    }
    __syncthreads();

    int cur = 0;
    for (int t = 0; t < 32; ++t) {
        const int tn = (t + 1) & 31;
#pragma unroll
        for (int j = 0; j < 2; ++j) {
            const int m = 2 * w + j;
            gload16(kA + (size_t)(tn * 64 + 8 * m) * 64, &Ks[cur ^ 1][8 * m * 64]);
            gload16(vA + (size_t)(8 * m) * 2048 + tn * 64, &Vs[cur ^ 1][8 * m * 64]);
        }

        const char* kbase = (const char*)&Ks[cur][0];
        f32x16 sacc0 = {}, sacc1 = {};
        __builtin_amdgcn_s_setprio(1);
#pragma unroll
        for (int s = 0; s < 4; ++s) {
            bf16x8 kf0 = *(const bf16x8*)(kbase + (col) * 128       + ((32 * s + 16 * h) ^ sw));
            bf16x8 kf1 = *(const bf16x8*)(kbase + (32 + col) * 128  + ((32 * s + 16 * h) ^ sw));
            sacc0 = __builtin_amdgcn_mfma_f32_32x32x16_bf16(kf0, qf[s], sacc0, 0, 0, 0);
            sacc1 = __builtin_amdgcn_mfma_f32_32x32x16_bf16(kf1, qf[s], sacc1, 0, 0, 0);
        }
        __builtin_amdgcn_s_setprio(0);

        f32x16 p0, p1;
#pragma unroll
        for (int r = 0; r < 16; ++r) { p0[r] = fexp2(sacc0[r]); }
#pragma unroll
        for (int r = 0; r < 16; ++r) { p1[r] = fexp2(sacc1[r]); }
#pragma unroll
        for (int r = 0; r < 16; ++r) { li += p0[r] + p1[r]; }

        bf16x8 pa0 = mk_pa(p0[0], p0[1], p0[2], p0[3], p0[4], p0[5], p0[6], p0[7]);
        bf16x8 pa1 = mk_pa(p0[8], p0[9], p0[10], p0[11], p0[12], p0[13], p0[14], p0[15]);
        bf16x8 pa2 = mk_pa(p1[0], p1[1], p1[2], p1[3], p1[4], p1[5], p1[6], p1[7]);
        bf16x8 pa3 = mk_pa(p1[8], p1[9], p1[10], p1[11], p1[12], p1[13], p1[14], p1[15]);

        const char* vb = (const char*)&Vs[cur][0];
        __builtin_amdgcn_s_setprio(1);
#pragma unroll
        for (int sg = 0; sg < 4; ++sg) {
            bf16x8 pf = sg == 0 ? pa0 : sg == 1 ? pa1 : sg == 2 ? pa2 : pa3;
            const int cb = (32 * sg + 16 * h) ^ sw;
            bf16x8 vf0 = *(const bf16x8*)(vb + (col) * 128      + cb);
            bf16x8 vf1 = *(const bf16x8*)(vb + (32 + col) * 128 + cb);
            o0 = __builtin_amdgcn_mfma_f32_32x32x16_bf16(pf, vf0, o0, 0, 0, 0);
            o1 = __builtin_amdgcn_mfma_f32_32x32x16_bf16(pf, vf1, o1, 0, 0, 0);
        }
        __builtin_amdgcn_s_setprio(0);

        __syncthreads();
        cur ^= 1;
    }

    li += __shfl_xor(li, 32);
    float inv = 1.0f / li;
#pragma unroll
    for (int reg = 0; reg < 16; ++reg) {
        const int crow = (reg & 3) + 8 * (reg >> 2) + 4 * h;
        float ivr = __shfl(inv, crow);
        const int row = qb + crow;
        u16* xp = Xa + ((size_t)b * 2048 + row) * 1024 + hd * 64;
        xp[col] = f2b(o0[reg] * ivr);
        xp[32 + col] = f2b(o1[reg] * ivr);
    }
}

// ---------------- launch --------------------------------------------------------
extern "C" void kernel_launch(void* const* d_in, const int* in_sizes, int n_in,
                              void* d_out, int out_size, void* d_ws, size_t ws_size,
                              hipStream_t stream) {
    const float* q   = (const float*)d_in[0];
    const float* k   = (const float*)d_in[1];
    const float* v   = (const float*)d_in[2];
    const float* Wq  = (const float*)d_in[3];
    const float* Wk  = (const float*)d_in[4];
    const float* Wv  = (const float*)d_in[5];
    const float* Wo  = (const float*)d_in[6];
    const float* bo  = (const float*)d_in[7];
    const float* qg  = (const float*)d_in[8];
    const float* qbt = (const float*)d_in[9];
    const float* kg  = (const float*)d_in[10];
    const float* kbt = (const float*)d_in[11];

    char* ws = (char*)d_ws;
    const float MUL_Q = 0.04508422002778f;   // (1/32) * log2(e)

    if (ws_size >= 109051904ULL) {
        // ---- fused layout: Wt | Ib3 (3 slots) | Pb3 (3 slots); LN/vt outputs
        //      reuse Ib3 (dead after gemm3); Xa reuses Pb3 slot 0.
        u16* Wt  = (u16*)(ws);                    //   0 ..  8,388,608
        u16* Ib3 = (u16*)(ws + 8388608);          //  .. 58,720,256
        u16* Pb3 = (u16*)(ws + 58720256);         //  .. 109,051,904
        u16* Qa  = (u16*)(ws + 8388608);          // over Ib3 slot 0
        u16* Ka  = (u16*)(ws + 25165824);         // over Ib3 slot 1
        u16* Vt  = (u16*)(ws + 41943040);         // over Ib3 slot 2
        u16* Xa  = Pb3;                           // over Pb3 slot 0

        wt_kernel<<<dim3(16, 16, 4), 256, 0, stream>>>(Wq, Wk, Wv, Wo, Wt);
        cvt3_kernel<<<dim3(4096, 1, 3), 256, 0, stream>>>(q, k, v, Ib3);
        gemm3_kernel<<<dim3(8, 64, 3), 256, 0, stream>>>(Ib3, Wt, Pb3);
        ln2_kernel<<<dim3(8192, 1, 2), 256, 0, stream>>>(Pb3, qg, qbt, kg, kbt, Qa, Ka, MUL_Q);
        vt_kernel<<<dim3(32, 64), 256, 0, stream>>>(Pb3 + 2 * 8388608, Vt);
        attn_kernel<<<1024, 256, 0, stream>>>(Qa, Ka, Vt, Xa);
        gemm_kernel<1><<<dim3(8, 64), 256, 0, stream>>>((const u16*)Xa, Wt + 3145728, nullptr, (float*)d_out, bo);
    } else {
        // ---- fallback: round-14 exact serial layout (92 MB)
        u16* Wt = (u16*)(ws);
        u16* Pb = (u16*)(ws + 8388608);
        u16* Qa = (u16*)(ws + 25165824);
        u16* Ka = (u16*)(ws + 41943040);
        u16* Vt = (u16*)(ws + 58720256);
        u16* Ib = (u16*)(ws + 75497472);
        u16* Xa = Pb;

        wt_kernel<<<dim3(16, 16, 4), 256, 0, stream>>>(Wq, Wk, Wv, Wo, Wt);
        cvt_kernel<<<4096, 256, 0, stream>>>(q, Ib);
        gemm_kernel<0><<<dim3(8, 64), 256, 0, stream>>>(Ib, Wt, Pb, nullptr, nullptr);
        ln_kernel<<<8192, 256, 0, stream>>>(Pb, qg, qbt, MUL_Q, Qa);
        cvt_kernel<<<4096, 256, 0, stream>>>(k, Ib);
        gemm_kernel<0><<<dim3(8, 64), 256, 0, stream>>>(Ib, Wt + 1048576, Pb, nullptr, nullptr);
        ln_kernel<<<8192, 256, 0, stream>>>(Pb, kg, kbt, 1.0f, Ka);
        cvt_kernel<<<4096, 256, 0, stream>>>(v, Ib);
        gemm_kernel<0><<<dim3(8, 64), 256, 0, stream>>>(Ib, Wt + 2097152, Pb, nullptr, nullptr);
        vt_kernel<<<dim3(32, 64), 256, 0, stream>>>(Pb, Vt);
        attn_kernel<<<1024, 256, 0, stream>>>(Qa, Ka, Vt, Xa);
        gemm_kernel<1><<<dim3(8, 64), 256, 0, stream>>>((const u16*)Xa, Wt + 3145728, nullptr, (float*)d_out, bo);
    }
}

// Round 16
// 240.197 us; speedup vs baseline: 1.1353x; 1.0085x over previous
//
#include <hip/hip_runtime.h>
#include <hip/hip_bf16.h>

typedef unsigned short u16;
typedef __attribute__((ext_vector_type(8))) short bf16x8;
typedef __attribute__((ext_vector_type(4))) float f32x4;
typedef __attribute__((ext_vector_type(16))) float f32x16;
typedef __attribute__((ext_vector_type(4))) unsigned short u16x4;
typedef __attribute__((ext_vector_type(4))) unsigned int u32x4;
typedef __attribute__((ext_vector_type(2))) int i32x2;

__device__ __forceinline__ u16 f2b(float f) {
    __hip_bfloat16 h = __float2bfloat16(f);
    u16 r; __builtin_memcpy(&r, &h, 2); return r;
}
__device__ __forceinline__ float bf2f(u16 u) {
    return __uint_as_float(((unsigned)u) << 16);
}
__device__ __forceinline__ void gload16(const void* g, void* l) {
    __builtin_amdgcn_global_load_lds(
        (const __attribute__((address_space(1))) unsigned int*)g,
        (__attribute__((address_space(3))) unsigned int*)l, 16, 0, 0);
}
// native HW exp2 via builtin (compiler-managed TRANS hazards; r13 lesson)
__device__ __forceinline__ float fexp2(float x) {
    return __builtin_amdgcn_exp2f(x);
}
__device__ __forceinline__ unsigned cvtpk(float lo, float hi) {
    unsigned d;
    asm("v_cvt_pk_bf16_f32 %0, %1, %2" : "=v"(d) : "v"(lo), "v"(hi));
    return d;
}
__device__ __forceinline__ bf16x8 mk_pa(float a0, float a1, float a2, float a3,
                                        float b0, float b1, float b2, float b3) {
    int A0 = (int)cvtpk(a0, a1), A1 = (int)cvtpk(a2, a3);
    int B0 = (int)cvtpk(b0, b1), B1 = (int)cvtpk(b2, b3);
    i32x2 r0 = __builtin_amdgcn_permlane32_swap(A0, B0, false, false);
    i32x2 r1 = __builtin_amdgcn_permlane32_swap(A1, B1, false, false);
    u32x4 fw = { (unsigned)r0[0], (unsigned)r1[0], (unsigned)r0[1], (unsigned)r1[1] };
    return __builtin_bit_cast(bf16x8, fw);
}

// ---------------- fp32 -> bf16 bulk convert (8 elems/thread) --------------------
__global__ __launch_bounds__(256)
void cvt_kernel(const float* __restrict__ in, u16* __restrict__ out) {
    size_t i = ((size_t)blockIdx.x * 256 + threadIdx.x) * 8;
    f32x4 a = *(const f32x4*)(in + i);
    f32x4 b = *(const f32x4*)(in + i + 4);
    u16x4 p0 = { f2b(a[0]), f2b(a[1]), f2b(a[2]), f2b(a[3]) };
    u16x4 p1 = { f2b(b[0]), f2b(b[1]), f2b(b[2]), f2b(b[3]) };
    *(u16x4*)(out + i) = p0;
    *(u16x4*)(out + i + 4) = p1;
}

// z=3 batched convert: q/k/v -> Ib3 slots
__global__ __launch_bounds__(256)
void cvt3_kernel(const float* __restrict__ q, const float* __restrict__ k,
                 const float* __restrict__ v, u16* __restrict__ out3) {
    const int z = blockIdx.z;
    const float* in = z == 0 ? q : z == 1 ? k : v;
    u16* out = out3 + (size_t)z * 8388608;
    size_t i = ((size_t)blockIdx.x * 256 + threadIdx.x) * 8;
    f32x4 a = *(const f32x4*)(in + i);
    f32x4 b = *(const f32x4*)(in + i + 4);
    u16x4 p0 = { f2b(a[0]), f2b(a[1]), f2b(a[2]), f2b(a[3]) };
    u16x4 p1 = { f2b(b[0]), f2b(b[1]), f2b(b[2]), f2b(b[3]) };
    *(u16x4*)(out + i) = p0;
    *(u16x4*)(out + i + 4) = p1;
}

// ---------------- weight transpose + convert: Wt[n][k] = bf16(W[k][n]) ----------
__global__ __launch_bounds__(256)
void wt_kernel(const float* __restrict__ Wq, const float* __restrict__ Wk,
               const float* __restrict__ Wv, const float* __restrict__ Wo,
               u16* __restrict__ Wt) {
    const float* W = blockIdx.z == 0 ? Wq : blockIdx.z == 1 ? Wk : blockIdx.z == 2 ? Wv : Wo;
    u16* Out = Wt + (size_t)blockIdx.z * (1024 * 1024);
    __shared__ float T[64][65];
    const int t = threadIdx.x;
    const int r0 = blockIdx.y * 64, c0 = blockIdx.x * 64;
#pragma unroll
    for (int e = 0; e < 4; ++e) {
        int row = e * 16 + (t >> 4), c4 = (t & 15) * 4;
        f32x4 v = *(const f32x4*)(W + (r0 + row) * 1024 + c0 + c4);
        T[row][c4] = v[0]; T[row][c4 + 1] = v[1]; T[row][c4 + 2] = v[2]; T[row][c4 + 3] = v[3];
    }
    __syncthreads();
#pragma unroll
    for (int e = 0; e < 4; ++e) {
        int orow = e * 16 + (t >> 4), oc4 = (t & 15) * 4;
        u16x4 pk = { f2b(T[oc4][orow]), f2b(T[oc4 + 1][orow]),
                     f2b(T[oc4 + 2][orow]), f2b(T[oc4 + 3][orow]) };
        *(u16x4*)(Out + (c0 + orow) * 1024 + r0 + oc4) = pk;
    }
}

// ---------------- GEMM core (round-7 proven): single-buffer LDS, gload16 DMA ----
template <int BIAS>
__device__ __forceinline__ void gemm_body(const u16* __restrict__ Ab,
                                          const u16* __restrict__ Bt,
                                          u16* __restrict__ Cb, float* __restrict__ Cf,
                                          const float* __restrict__ bias,
                                          u16* As, u16* Bs, int bx, int by) {
    constexpr int K = 1024;
    const int tid = threadIdx.x;
    const int lane = tid & 63, w = tid >> 6;
    const int wr = w >> 1, wc = w & 1;
    const int c = lane & 15, g = lane >> 4;
    const int m0 = by * 128, n0 = bx * 128;
    const int sr = lane >> 3, sc = (lane & 7) * 8;
    f32x4 acc[4][4] = {};
    for (int kt = 0; kt < 16; ++kt) {
        const int k0 = kt * 64;
#pragma unroll
        for (int i = 0; i < 4; ++i) {
            int row = 32 * w + 8 * i;
            gload16(Ab + (size_t)(m0 + row + sr) * K + k0 + sc, &As[row * 64]);
            gload16(Bt + (size_t)(n0 + row + sr) * K + k0 + sc, &Bs[row * 64]);
        }
        __syncthreads();
#pragma unroll
        for (int kk = 0; kk < 2; ++kk) {
            bf16x8 af[4], bfr[4];
#pragma unroll
            for (int m = 0; m < 4; ++m)
                af[m] = *(const bf16x8*)&As[(wr * 64 + m * 16 + c) * 64 + kk * 32 + 8 * g];
#pragma unroll
            for (int n = 0; n < 4; ++n)
                bfr[n] = *(const bf16x8*)&Bs[(wc * 64 + n * 16 + c) * 64 + kk * 32 + 8 * g];
#pragma unroll
            for (int m = 0; m < 4; ++m)
#pragma unroll
                for (int n = 0; n < 4; ++n)
                    acc[m][n] = __builtin_amdgcn_mfma_f32_16x16x32_bf16(af[m], bfr[n], acc[m][n], 0, 0, 0);
        }
        __syncthreads();
    }
#pragma unroll
    for (int n = 0; n < 4; ++n) {
        int col = n0 + wc * 64 + n * 16 + c;
        float bv = BIAS ? bias[col] : 0.0f;
#pragma unroll
        for (int m = 0; m < 4; ++m) {
            int row0 = m0 + wr * 64 + m * 16 + 4 * g;
#pragma unroll
            for (int r = 0; r < 4; ++r) {
                if (BIAS) Cf[(row0 + r) * 1024 + col] = acc[m][n][r] + bv;
                else      Cb[(row0 + r) * 1024 + col] = f2b(acc[m][n][r]);
            }
        }
    }
}

// final GEMM (bias, f32 out), XCD-remapped 1D grid of 512 blocks:
// bx=(B>>3)&7, by=(B&7)+8*(B>>6) -> all 8 blocks sharing an A-panel (same by)
// have B===by (mod 8) -> same XCD -> A-panel fetched into ONE L2.
__global__ __launch_bounds__(256)
void gemm_kernel_f(const u16* __restrict__ Ab, const u16* __restrict__ Bt,
                   float* __restrict__ Cf, const float* __restrict__ bias) {
    __shared__ u16 As[128 * 64];
    __shared__ u16 Bs[128 * 64];
    const int B = blockIdx.x;
    const int bx = (B >> 3) & 7;
    const int by = (B & 7) + 8 * (B >> 6);
    gemm_body<1>(Ab, Bt, nullptr, Cf, bias, As, Bs, bx, by);
}

// z=3 batched projection GEMM, XCD-remapped 1D grid of 1536 blocks:
// panel p=(B&7)+8*(B>>6) in [0,192) -> by=p&63, z=p>>6; member bx=(B>>3)&7.
// All 8 members of panel p share XCD p&7 (B===p mod 8). Bijective (1536=8*192).
__global__ __launch_bounds__(256)
void gemm3_kernel(const u16* __restrict__ A3, const u16* __restrict__ Wt,
                  u16* __restrict__ C3) {
    __shared__ u16 As[128 * 64];
    __shared__ u16 Bs[128 * 64];
    const int B = blockIdx.x;
    const int bx = (B >> 3) & 7;
    const int p = (B & 7) + 8 * (B >> 6);
    const int by = p & 63;
    const int z = p >> 6;
    gemm_body<0>(A3 + (size_t)z * 8388608, Wt + (size_t)z * 1048576,
                 C3 + (size_t)z * 8388608, nullptr, nullptr, As, Bs, bx, by);
}

// ---------------- LayerNorm over D=1024 (bf16 in), write bf16 [bh][s][hd] -------
__device__ __forceinline__ void ln_body(const u16* __restrict__ P,
                                        const float* __restrict__ gamma,
                                        const float* __restrict__ beta,
                                        float mul, u16* __restrict__ Out) {
    const int row = blockIdx.x;
    const int tid = threadIdx.x;
    const int lane = tid & 63, w = tid >> 6;
    u16x4 xr = *(const u16x4*)(P + row * 1024 + tid * 4);
    float x0 = bf2f(xr[0]), x1 = bf2f(xr[1]), x2 = bf2f(xr[2]), x3 = bf2f(xr[3]);
    float s = x0 + x1 + x2 + x3;
    float sq = x0 * x0 + x1 * x1 + x2 * x2 + x3 * x3;
#pragma unroll
    for (int m = 1; m < 64; m <<= 1) { s += __shfl_xor(s, m); sq += __shfl_xor(sq, m); }
    __shared__ float red[8];
    if (lane == 0) { red[w] = s; red[4 + w] = sq; }
    __syncthreads();
    float st = red[0] + red[1] + red[2] + red[3];
    float sqt = red[4] + red[5] + red[6] + red[7];
    float mu = st * (1.0f / 1024.0f);
    float var = sqt * (1.0f / 1024.0f) - mu * mu;
    float rs = rsqrtf(var + 1e-5f);
    f32x4 gm = *(const f32x4*)(gamma + tid * 4);
    f32x4 bt = *(const f32x4*)(beta + tid * 4);
    float xs[4] = {x0, x1, x2, x3};
    u16x4 pk;
#pragma unroll
    for (int j = 0; j < 4; ++j)
        pk[j] = f2b(((xs[j] - mu) * rs * gm[j] + bt[j]) * mul);
    const int b = row >> 11, sI = row & 2047;
    const int col = tid * 4, hh = col >> 6, d = col & 63;
    *(u16x4*)(Out + (((b * 16 + hh) * 2048 + sI) << 6) + d) = pk;
}

__global__ __launch_bounds__(256)
void ln_kernel(const u16* __restrict__ P, const float* __restrict__ gamma,
               const float* __restrict__ beta, float mul, u16* __restrict__ Out) {
    ln_body(P, gamma, beta, mul, Out);
}

// z=2 batched LN: z=0 -> q (MUL_Q), z=1 -> k (1.0)
__global__ __launch_bounds__(256)
void ln2_kernel(const u16* __restrict__ P3,
                const float* __restrict__ qg, const float* __restrict__ qb,
                const float* __restrict__ kg, const float* __restrict__ kb,
                u16* __restrict__ Qa, u16* __restrict__ Ka, float mulq) {
    const int z = blockIdx.z;
    ln_body(P3 + (size_t)z * 8388608, z == 0 ? qg : kg, z == 0 ? qb : kb,
            z == 0 ? mulq : 1.0f, z == 0 ? Qa : Ka);
}

// ---------------- V transpose: Vt[bh][64][S] (bf16 in/out) ----------------------
__global__ __launch_bounds__(256)
void vt_kernel(const u16* __restrict__ P, u16* __restrict__ Vt) {
    __shared__ u16 T[64][72];
    const int t = threadIdx.x;
    const int bh = blockIdx.y, s0 = blockIdx.x * 64;
    const int b = bh >> 4, h = bh & 15;
#pragma unroll
    for (int e = 0; e < 4; ++e) {
        int row = e * 16 + (t >> 4), c4 = (t & 15) * 4;
        u16x4 v = *(const u16x4*)(P + (b * 2048 + s0 + row) * 1024 + h * 64 + c4);
        *(u16x4*)&T[row][c4] = v;
    }
    __syncthreads();
#pragma unroll
    for (int e = 0; e < 4; ++e) {
        int dd = e * 16 + (t >> 4), s4 = (t & 15) * 4;
        u16x4 pk = { T[s4][dd], T[s4 + 1][dd], T[s4 + 2][dd], T[s4 + 3][dd] };
        *(u16x4*)(Vt + ((size_t)bh * 64 + dd) * 2048 + s0 + s4) = pk;
    }
}

// ---------------- flash attention v7.3 (round-14 exact) -------------------------
__global__ __launch_bounds__(256, 4)
void attn_kernel(const u16* __restrict__ Qa, const u16* __restrict__ Ka,
                 const u16* __restrict__ Vt, u16* __restrict__ Xa) {
    __shared__ u16 Ks[2][4096];
    __shared__ u16 Vs[2][4096];
    const int tid = threadIdx.x;
    const int lane = tid & 63, w = tid >> 6;
    const int col = lane & 31, h = lane >> 5;
    const int bid = blockIdx.x;
    const int bh = (bid & 7) * 8 + ((bid >> 3) & 7);
    const int q0 = (bid >> 6) * 128;
    const int b = bh >> 4, hd = bh & 15;
    const int qb = q0 + w * 32;
    const int sw = (col & 7) << 4;

    const u16* qptr = Qa + ((size_t)bh * 2048 + qb + col) * 64;
    bf16x8 qf[4];
#pragma unroll
    for (int s = 0; s < 4; ++s)
        qf[s] = *(const bf16x8*)(qptr + 16 * s + 8 * h);

    const int sr = lane >> 3;
    const int scg = ((lane & 7) ^ sr) * 8;
    const u16* kA = Ka + ((size_t)bh * 2048 + sr) * 64 + scg;
    const u16* vA = Vt + ((size_t)bh * 64 + sr) * 2048 + scg;

    f32x16 o0 = {}, o1 = {};
    float li = 0.f;

#pragma unroll
    for (int j = 0; j < 2; ++j) {
        const int m = 2 * w + j;
        gload16(kA + (size_t)(8 * m) * 64, &Ks[0][8 * m * 64]);
        gload16(vA + (size_t)(8 * m) * 2048, &Vs[0][8 * m * 64]);
    }
    __syncthreads();

    int cur = 0;
    for (int t = 0; t < 32; ++t) {
        const int tn = (t + 1) & 31;
#pragma unroll
        for (int j = 0; j < 2; ++j) {
            const int m = 2 * w + j;
            gload16(kA + (size_t)(tn * 64 + 8 * m) * 64, &Ks[cur ^ 1][8 * m * 64]);
            gload16(vA + (size_t)(8 * m) * 2048 + tn * 64, &Vs[cur ^ 1][8 * m * 64]);
        }

        const char* kbase = (const char*)&Ks[cur][0];
        f32x16 sacc0 = {}, sacc1 = {};
        __builtin_amdgcn_s_setprio(1);
#pragma unroll
        for (int s = 0; s < 4; ++s) {
            bf16x8 kf0 = *(const bf16x8*)(kbase + (col) * 128       + ((32 * s + 16 * h) ^ sw));
            bf16x8 kf1 = *(const bf16x8*)(kbase + (32 + col) * 128  + ((32 * s + 16 * h) ^ sw));
            sacc0 = __builtin_amdgcn_mfma_f32_32x32x16_bf16(kf0, qf[s], sacc0, 0, 0, 0);
            sacc1 = __builtin_amdgcn_mfma_f32_32x32x16_bf16(kf1, qf[s], sacc1, 0, 0, 0);
        }
        __builtin_amdgcn_s_setprio(0);

        f32x16 p0, p1;
#pragma unroll
        for (int r = 0; r < 16; ++r) { p0[r] = fexp2(sacc0[r]); }
#pragma unroll
        for (int r = 0; r < 16; ++r) { p1[r] = fexp2(sacc1[r]); }
#pragma unroll
        for (int r = 0; r < 16; ++r) { li += p0[r] + p1[r]; }

        bf16x8 pa0 = mk_pa(p0[0], p0[1], p0[2], p0[3], p0[4], p0[5], p0[6], p0[7]);
        bf16x8 pa1 = mk_pa(p0[8], p0[9], p0[10], p0[11], p0[12], p0[13], p0[14], p0[15]);
        bf16x8 pa2 = mk_pa(p1[0], p1[1], p1[2], p1[3], p1[4], p1[5], p1[6], p1[7]);
        bf16x8 pa3 = mk_pa(p1[8], p1[9], p1[10], p1[11], p1[12], p1[13], p1[14], p1[15]);

        const char* vb = (const char*)&Vs[cur][0];
        __builtin_amdgcn_s_setprio(1);
#pragma unroll
        for (int sg = 0; sg < 4; ++sg) {
            bf16x8 pf = sg == 0 ? pa0 : sg == 1 ? pa1 : sg == 2 ? pa2 : pa3;
            const int cb = (32 * sg + 16 * h) ^ sw;
            bf16x8 vf0 = *(const bf16x8*)(vb + (col) * 128      + cb);
            bf16x8 vf1 = *(const bf16x8*)(vb + (32 + col) * 128 + cb);
            o0 = __builtin_amdgcn_mfma_f32_32x32x16_bf16(pf, vf0, o0, 0, 0, 0);
            o1 = __builtin_amdgcn_mfma_f32_32x32x16_bf16(pf, vf1, o1, 0, 0, 0);
        }
        __builtin_amdgcn_s_setprio(0);

        __syncthreads();
        cur ^= 1;
    }

    li += __shfl_xor(li, 32);
    float inv = 1.0f / li;
#pragma unroll
    for (int reg = 0; reg < 16; ++reg) {
        const int crow = (reg & 3) + 8 * (reg >> 2) + 4 * h;
        float ivr = __shfl(inv, crow);
        const int row = qb + crow;
        u16* xp = Xa + ((size_t)b * 2048 + row) * 1024 + hd * 64;
        xp[col] = f2b(o0[reg] * ivr);
        xp[32 + col] = f2b(o1[reg] * ivr);
    }
}

// ---------------- launch --------------------------------------------------------
extern "C" void kernel_launch(void* const* d_in, const int* in_sizes, int n_in,
                              void* d_out, int out_size, void* d_ws, size_t ws_size,
                              hipStream_t stream) {
    const float* q   = (const float*)d_in[0];
    const float* k   = (const float*)d_in[1];
    const float* v   = (const float*)d_in[2];
    const float* Wq  = (const float*)d_in[3];
    const float* Wk  = (const float*)d_in[4];
    const float* Wv  = (const float*)d_in[5];
    const float* Wo  = (const float*)d_in[6];
    const float* bo  = (const float*)d_in[7];
    const float* qg  = (const float*)d_in[8];
    const float* qbt = (const float*)d_in[9];
    const float* kg  = (const float*)d_in[10];
    const float* kbt = (const float*)d_in[11];

    char* ws = (char*)d_ws;
    const float MUL_Q = 0.04508422002778f;   // (1/32) * log2(e)

    if (ws_size >= 109051904ULL) {
        u16* Wt  = (u16*)(ws);
        u16* Ib3 = (u16*)(ws + 8388608);
        u16* Pb3 = (u16*)(ws + 58720256);
        u16* Qa  = (u16*)(ws + 8388608);
        u16* Ka  = (u16*)(ws + 25165824);
        u16* Vt  = (u16*)(ws + 41943040);
        u16* Xa  = Pb3;

        wt_kernel<<<dim3(16, 16, 4), 256, 0, stream>>>(Wq, Wk, Wv, Wo, Wt);
        cvt3_kernel<<<dim3(4096, 1, 3), 256, 0, stream>>>(q, k, v, Ib3);
        gemm3_kernel<<<1536, 256, 0, stream>>>(Ib3, Wt, Pb3);
        ln2_kernel<<<dim3(8192, 1, 2), 256, 0, stream>>>(Pb3, qg, qbt, kg, kbt, Qa, Ka, MUL_Q);
        vt_kernel<<<dim3(32, 64), 256, 0, stream>>>(Pb3 + 2 * 8388608, Vt);
        attn_kernel<<<1024, 256, 0, stream>>>(Qa, Ka, Vt, Xa);
        gemm_kernel_f<<<512, 256, 0, stream>>>((const u16*)Xa, Wt + 3145728, (float*)d_out, bo);
    } else {
        // fallback: serial layout (92 MB), same kernels
        u16* Wt = (u16*)(ws);
        u16* Pb = (u16*)(ws + 8388608);
        u16* Qa = (u16*)(ws + 25165824);
        u16* Ka = (u16*)(ws + 41943040);
        u16* Vt = (u16*)(ws + 58720256);
        u16* Ib = (u16*)(ws + 75497472);
        u16* Xa = Pb;

        wt_kernel<<<dim3(16, 16, 4), 256, 0, stream>>>(Wq, Wk, Wv, Wo, Wt);
        cvt_kernel<<<4096, 256, 0, stream>>>(q, Ib);
        gemm3_kernel<<<512, 256, 0, stream>>>(Ib, Wt, Pb);   // z decoded 0 only when grid=512
        ln_kernel<<<8192, 256, 0, stream>>>(Pb, qg, qbt, MUL_Q, Qa);
        cvt_kernel<<<4096, 256, 0, stream>>>(k, Ib);
        gemm3_kernel<<<512, 256, 0, stream>>>(Ib, Wt + 1048576, Pb);
        ln_kernel<<<8192, 256, 0, stream>>>(Pb, kg, kbt, 1.0f, Ka);
        cvt_kernel<<<4096, 256, 0, stream>>>(v, Ib);
        gemm3_kernel<<<512, 256, 0, stream>>>(Ib, Wt + 2097152, Pb);
        vt_kernel<<<dim3(32, 64), 256, 0, stream>>>(Pb, Vt);
        attn_kernel<<<1024, 256, 0, stream>>>(Qa, Ka, Vt, Xa);
        gemm_kernel_f<<<512, 256, 0, stream>>>((const u16*)Xa, Wt + 3145728, (float*)d_out, bo);
    }
}

// Round 17
// 228.111 us; speedup vs baseline: 1.1954x; 1.0530x over previous
//
#include <hip/hip_runtime.h>
#include <hip/hip_bf16.h>

typedef unsigned short u16;
typedef __attribute__((ext_vector_type(8))) short bf16x8;
typedef __attribute__((ext_vector_type(4))) float f32x4;
typedef __attribute__((ext_vector_type(16))) float f32x16;
typedef __attribute__((ext_vector_type(4))) unsigned short u16x4;
typedef __attribute__((ext_vector_type(4))) unsigned int u32x4;
typedef __attribute__((ext_vector_type(2))) int i32x2;

__device__ __forceinline__ u16 f2b(float f) {
    __hip_bfloat16 h = __float2bfloat16(f);
    u16 r; __builtin_memcpy(&r, &h, 2); return r;
}
__device__ __forceinline__ float bf2f(u16 u) {
    return __uint_as_float(((unsigned)u) << 16);
}
__device__ __forceinline__ void gload16(const void* g, void* l) {
    __builtin_amdgcn_global_load_lds(
        (const __attribute__((address_space(1))) unsigned int*)g,
        (__attribute__((address_space(3))) unsigned int*)l, 16, 0, 0);
}
// native HW exp2 via builtin (compiler-managed TRANS hazards; r13 lesson)
__device__ __forceinline__ float fexp2(float x) {
    return __builtin_amdgcn_exp2f(x);
}
__device__ __forceinline__ unsigned cvtpk(float lo, float hi) {
    unsigned d;
    asm("v_cvt_pk_bf16_f32 %0, %1, %2" : "=v"(d) : "v"(lo), "v"(hi));
    return d;
}
__device__ __forceinline__ bf16x8 mk_pa(float a0, float a1, float a2, float a3,
                                        float b0, float b1, float b2, float b3) {
    int A0 = (int)cvtpk(a0, a1), A1 = (int)cvtpk(a2, a3);
    int B0 = (int)cvtpk(b0, b1), B1 = (int)cvtpk(b2, b3);
    i32x2 r0 = __builtin_amdgcn_permlane32_swap(A0, B0, false, false);
    i32x2 r1 = __builtin_amdgcn_permlane32_swap(A1, B1, false, false);
    u32x4 fw = { (unsigned)r0[0], (unsigned)r1[0], (unsigned)r0[1], (unsigned)r1[1] };
    return __builtin_bit_cast(bf16x8, fw);
}

// ---------------- weight transpose + convert: Wt[n][k] = bf16(W[k][n]) ----------
__global__ __launch_bounds__(256)
void wt_kernel(const float* __restrict__ Wq, const float* __restrict__ Wk,
               const float* __restrict__ Wv, const float* __restrict__ Wo,
               u16* __restrict__ Wt) {
    const float* W = blockIdx.z == 0 ? Wq : blockIdx.z == 1 ? Wk : blockIdx.z == 2 ? Wv : Wo;
    u16* Out = Wt + (size_t)blockIdx.z * (1024 * 1024);
    __shared__ float T[64][65];
    const int t = threadIdx.x;
    const int r0 = blockIdx.y * 64, c0 = blockIdx.x * 64;
#pragma unroll
    for (int e = 0; e < 4; ++e) {
        int row = e * 16 + (t >> 4), c4 = (t & 15) * 4;
        f32x4 v = *(const f32x4*)(W + (r0 + row) * 1024 + c0 + c4);
        T[row][c4] = v[0]; T[row][c4 + 1] = v[1]; T[row][c4 + 2] = v[2]; T[row][c4 + 3] = v[3];
    }
    __syncthreads();
#pragma unroll
    for (int e = 0; e < 4; ++e) {
        int orow = e * 16 + (t >> 4), oc4 = (t & 15) * 4;
        u16x4 pk = { f2b(T[oc4][orow]), f2b(T[oc4 + 1][orow]),
                     f2b(T[oc4 + 2][orow]), f2b(T[oc4 + 3][orow]) };
        *(u16x4*)(Out + (c0 + orow) * 1024 + r0 + oc4) = pk;
    }
}

// ---------------- GEMM core: single-buffer LDS; A staged f32->bf16 (AF32) or DMA
template <int AF32, int BIAS>
__device__ __forceinline__ void gemm_body(const void* __restrict__ Av,
                                          const u16* __restrict__ Bt,
                                          u16* __restrict__ Cb, float* __restrict__ Cf,
                                          const float* __restrict__ bias,
                                          u16* As, u16* Bs, int bx, int by) {
    constexpr int K = 1024;
    const int tid = threadIdx.x;
    const int lane = tid & 63, w = tid >> 6;
    const int wr = w >> 1, wc = w & 1;
    const int c = lane & 15, g = lane >> 4;
    const int m0 = by * 128, n0 = bx * 128;
    const int sr = lane >> 3, sc = (lane & 7) * 8;
    const float* Af = (const float*)Av;
    const u16* Ab = (const u16*)Av;
    f32x4 acc[4][4] = {};
    for (int kt = 0; kt < 16; ++kt) {
        const int k0 = kt * 64;
        if (AF32) {
            // reg-staged fp32 A with fused cvt (r2-r7 proven: same speed as DMA,
            // conversion VALU hides in the latency-bound staging phase)
#pragma unroll
            for (int i = 0; i < 8; ++i) {
                int idx = i * 256 + tid;
                int row = idx >> 4, c4 = (idx & 15) * 4;
                f32x4 v = *(const f32x4*)(Af + (size_t)(m0 + row) * K + k0 + c4);
                u16x4 pk = { f2b(v[0]), f2b(v[1]), f2b(v[2]), f2b(v[3]) };
                *(u16x4*)&As[row * 64 + c4] = pk;
            }
        } else {
#pragma unroll
            for (int i = 0; i < 4; ++i) {
                int row = 32 * w + 8 * i;
                gload16(Ab + (size_t)(m0 + row + sr) * K + k0 + sc, &As[row * 64]);
            }
        }
#pragma unroll
        for (int i = 0; i < 4; ++i) {
            int row = 32 * w + 8 * i;
            gload16(Bt + (size_t)(n0 + row + sr) * K + k0 + sc, &Bs[row * 64]);
        }
        __syncthreads();
#pragma unroll
        for (int kk = 0; kk < 2; ++kk) {
            bf16x8 af[4], bfr[4];
#pragma unroll
            for (int m = 0; m < 4; ++m)
                af[m] = *(const bf16x8*)&As[(wr * 64 + m * 16 + c) * 64 + kk * 32 + 8 * g];
#pragma unroll
            for (int n = 0; n < 4; ++n)
                bfr[n] = *(const bf16x8*)&Bs[(wc * 64 + n * 16 + c) * 64 + kk * 32 + 8 * g];
#pragma unroll
            for (int m = 0; m < 4; ++m)
#pragma unroll
                for (int n = 0; n < 4; ++n)
                    acc[m][n] = __builtin_amdgcn_mfma_f32_16x16x32_bf16(af[m], bfr[n], acc[m][n], 0, 0, 0);
        }
        __syncthreads();
    }
#pragma unroll
    for (int n = 0; n < 4; ++n) {
        int col = n0 + wc * 64 + n * 16 + c;
        float bv = BIAS ? bias[col] : 0.0f;
#pragma unroll
        for (int m = 0; m < 4; ++m) {
            int row0 = m0 + wr * 64 + m * 16 + 4 * g;
#pragma unroll
            for (int r = 0; r < 4; ++r) {
                if (BIAS) Cf[(row0 + r) * 1024 + col] = acc[m][n][r] + bv;
                else      Cb[(row0 + r) * 1024 + col] = f2b(acc[m][n][r]);
            }
        }
    }
}

// final GEMM (bias, f32 out, bf16 A), XCD-remapped 1D grid of 512 blocks
__global__ __launch_bounds__(256)
void gemm_kernel_f(const u16* __restrict__ Ab, const u16* __restrict__ Bt,
                   float* __restrict__ Cf, const float* __restrict__ bias) {
    __shared__ u16 As[128 * 64];
    __shared__ u16 Bs[128 * 64];
    const int B = blockIdx.x;
    const int bx = (B >> 3) & 7;
    const int by = (B & 7) + 8 * (B >> 6);
    gemm_body<0, 1>(Ab, Bt, nullptr, Cf, bias, As, Bs, bx, by);
}

// z=3 batched projection GEMM with FUSED f32->bf16 A conversion.
// XCD-remapped 1D grid of 1536 blocks: panel p=(B&7)+8*(B>>6) in [0,192),
// by=p&63, z=p>>6, member bx=(B>>3)&7; all 8 members of a panel share XCD p&7.
__global__ __launch_bounds__(256)
void gemm3_kernel(const float* __restrict__ q, const float* __restrict__ k,
                  const float* __restrict__ v, const u16* __restrict__ Wt,
                  u16* __restrict__ C3) {
    __shared__ u16 As[128 * 64];
    __shared__ u16 Bs[128 * 64];
    const int B = blockIdx.x;
    const int bx = (B >> 3) & 7;
    const int p = (B & 7) + 8 * (B >> 6);
    const int by = p & 63;
    const int z = p >> 6;
    const float* Af = z == 0 ? q : z == 1 ? k : v;
    gemm_body<1, 0>((const void*)Af, Wt + (size_t)z * 1048576,
                    C3 + (size_t)z * 8388608, nullptr, nullptr, As, Bs, bx, by);
}

// single fused-A GEMM (fallback path), XCD-remapped 512 blocks
__global__ __launch_bounds__(256)
void gemm1_kernel(const float* __restrict__ Af, const u16* __restrict__ Bt,
                  u16* __restrict__ Cb) {
    __shared__ u16 As[128 * 64];
    __shared__ u16 Bs[128 * 64];
    const int B = blockIdx.x;
    const int bx = (B >> 3) & 7;
    const int by = (B & 7) + 8 * (B >> 6);
    gemm_body<1, 0>((const void*)Af, Bt, Cb, nullptr, nullptr, As, Bs, bx, by);
}

// ---------------- LayerNorm over D=1024 (bf16 in), write bf16 [bh][s][hd] -------
__device__ __forceinline__ void ln_body(const u16* __restrict__ P,
                                        const float* __restrict__ gamma,
                                        const float* __restrict__ beta,
                                        float mul, u16* __restrict__ Out) {
    const int row = blockIdx.x;
    const int tid = threadIdx.x;
    const int lane = tid & 63, w = tid >> 6;
    u16x4 xr = *(const u16x4*)(P + row * 1024 + tid * 4);
    float x0 = bf2f(xr[0]), x1 = bf2f(xr[1]), x2 = bf2f(xr[2]), x3 = bf2f(xr[3]);
    float s = x0 + x1 + x2 + x3;
    float sq = x0 * x0 + x1 * x1 + x2 * x2 + x3 * x3;
#pragma unroll
    for (int m = 1; m < 64; m <<= 1) { s += __shfl_xor(s, m); sq += __shfl_xor(sq, m); }
    __shared__ float red[8];
    if (lane == 0) { red[w] = s; red[4 + w] = sq; }
    __syncthreads();
    float st = red[0] + red[1] + red[2] + red[3];
    float sqt = red[4] + red[5] + red[6] + red[7];
    float mu = st * (1.0f / 1024.0f);
    float var = sqt * (1.0f / 1024.0f) - mu * mu;
    float rs = rsqrtf(var + 1e-5f);
    f32x4 gm = *(const f32x4*)(gamma + tid * 4);
    f32x4 bt = *(const f32x4*)(beta + tid * 4);
    float xs[4] = {x0, x1, x2, x3};
    u16x4 pk;
#pragma unroll
    for (int j = 0; j < 4; ++j)
        pk[j] = f2b(((xs[j] - mu) * rs * gm[j] + bt[j]) * mul);
    const int b = row >> 11, sI = row & 2047;
    const int col = tid * 4, hh = col >> 6, d = col & 63;
    *(u16x4*)(Out + (((b * 16 + hh) * 2048 + sI) << 6) + d) = pk;
}

__global__ __launch_bounds__(256)
void ln_kernel(const u16* __restrict__ P, const float* __restrict__ gamma,
               const float* __restrict__ beta, float mul, u16* __restrict__ Out) {
    ln_body(P, gamma, beta, mul, Out);
}

// z=2 batched LN: z=0 -> q (MUL_Q), z=1 -> k (1.0)
__global__ __launch_bounds__(256)
void ln2_kernel(const u16* __restrict__ P3,
                const float* __restrict__ qg, const float* __restrict__ qb,
                const float* __restrict__ kg, const float* __restrict__ kb,
                u16* __restrict__ Qa, u16* __restrict__ Ka, float mulq) {
    const int z = blockIdx.z;
    ln_body(P3 + (size_t)z * 8388608, z == 0 ? qg : kg, z == 0 ? qb : kb,
            z == 0 ? mulq : 1.0f, z == 0 ? Qa : Ka);
}

// ---------------- V transpose: Vt[bh][64][S] (bf16 in/out) ----------------------
__global__ __launch_bounds__(256)
void vt_kernel(const u16* __restrict__ P, u16* __restrict__ Vt) {
    __shared__ u16 T[64][72];
    const int t = threadIdx.x;
    const int bh = blockIdx.y, s0 = blockIdx.x * 64;
    const int b = bh >> 4, h = bh & 15;
#pragma unroll
    for (int e = 0; e < 4; ++e) {
        int row = e * 16 + (t >> 4), c4 = (t & 15) * 4;
        u16x4 v = *(const u16x4*)(P + (b * 2048 + s0 + row) * 1024 + h * 64 + c4);
        *(u16x4*)&T[row][c4] = v;
    }
    __syncthreads();
#pragma unroll
    for (int e = 0; e < 4; ++e) {
        int dd = e * 16 + (t >> 4), s4 = (t & 15) * 4;
        u16x4 pk = { T[s4][dd], T[s4 + 1][dd], T[s4 + 2][dd], T[s4 + 3][dd] };
        *(u16x4*)(Vt + ((size_t)bh * 64 + dd) * 2048 + s0 + s4) = pk;
    }
}

// ---------------- flash attention v7.3 (round-14 exact) -------------------------
__global__ __launch_bounds__(256, 4)
void attn_kernel(const u16* __restrict__ Qa, const u16* __restrict__ Ka,
                 const u16* __restrict__ Vt, u16* __restrict__ Xa) {
    __shared__ u16 Ks[2][4096];
    __shared__ u16 Vs[2][4096];
    const int tid = threadIdx.x;
    const int lane = tid & 63, w = tid >> 6;
    const int col = lane & 31, h = lane >> 5;
    const int bid = blockIdx.x;
    const int bh = (bid & 7) * 8 + ((bid >> 3) & 7);
    const int q0 = (bid >> 6) * 128;
    const int b = bh >> 4, hd = bh & 15;
    const int qb = q0 + w * 32;
    const int sw = (col & 7) << 4;

    const u16* qptr = Qa + ((size_t)bh * 2048 + qb + col) * 64;
    bf16x8 qf[4];
#pragma unroll
    for (int s = 0; s < 4; ++s)
        qf[s] = *(const bf16x8*)(qptr + 16 * s + 8 * h);

    const int sr = lane >> 3;
    const int scg = ((lane & 7) ^ sr) * 8;
    const u16* kA = Ka + ((size_t)bh * 2048 + sr) * 64 + scg;
    const u16* vA = Vt + ((size_t)bh * 64 + sr) * 2048 + scg;

    f32x16 o0 = {}, o1 = {};
    float li = 0.f;

#pragma unroll
    for (int j = 0; j < 2; ++j) {
        const int m = 2 * w + j;
        gload16(kA + (size_t)(8 * m) * 64, &Ks[0][8 * m * 64]);
        gload16(vA + (size_t)(8 * m) * 2048, &Vs[0][8 * m * 64]);
    }
    __syncthreads();

    int cur = 0;
    for (int t = 0; t < 32; ++t) {
        const int tn = (t + 1) & 31;
#pragma unroll
        for (int j = 0; j < 2; ++j) {
            const int m = 2 * w + j;
            gload16(kA + (size_t)(tn * 64 + 8 * m) * 64, &Ks[cur ^ 1][8 * m * 64]);
            gload16(vA + (size_t)(8 * m) * 2048 + tn * 64, &Vs[cur ^ 1][8 * m * 64]);
        }

        const char* kbase = (const char*)&Ks[cur][0];
        f32x16 sacc0 = {}, sacc1 = {};
        __builtin_amdgcn_s_setprio(1);
#pragma unroll
        for (int s = 0; s < 4; ++s) {
            bf16x8 kf0 = *(const bf16x8*)(kbase + (col) * 128       + ((32 * s + 16 * h) ^ sw));
            bf16x8 kf1 = *(const bf16x8*)(kbase + (32 + col) * 128  + ((32 * s + 16 * h) ^ sw));
            sacc0 = __builtin_amdgcn_mfma_f32_32x32x16_bf16(kf0, qf[s], sacc0, 0, 0, 0);
            sacc1 = __builtin_amdgcn_mfma_f32_32x32x16_bf16(kf1, qf[s], sacc1, 0, 0, 0);
        }
        __builtin_amdgcn_s_setprio(0);

        f32x16 p0, p1;
#pragma unroll
        for (int r = 0; r < 16; ++r) { p0[r] = fexp2(sacc0[r]); }
#pragma unroll
        for (int r = 0; r < 16; ++r) { p1[r] = fexp2(sacc1[r]); }
#pragma unroll
        for (int r = 0; r < 16; ++r) { li += p0[r] + p1[r]; }

        bf16x8 pa0 = mk_pa(p0[0], p0[1], p0[2], p0[3], p0[4], p0[5], p0[6], p0[7]);
        bf16x8 pa1 = mk_pa(p0[8], p0[9], p0[10], p0[11], p0[12], p0[13], p0[14], p0[15]);
        bf16x8 pa2 = mk_pa(p1[0], p1[1], p1[2], p1[3], p1[4], p1[5], p1[6], p1[7]);
        bf16x8 pa3 = mk_pa(p1[8], p1[9], p1[10], p1[11], p1[12], p1[13], p1[14], p1[15]);

        const char* vb = (const char*)&Vs[cur][0];
        __builtin_amdgcn_s_setprio(1);
#pragma unroll
        for (int sg = 0; sg < 4; ++sg) {
            bf16x8 pf = sg == 0 ? pa0 : sg == 1 ? pa1 : sg == 2 ? pa2 : pa3;
            const int cb = (32 * sg + 16 * h) ^ sw;
            bf16x8 vf0 = *(const bf16x8*)(vb + (col) * 128      + cb);
            bf16x8 vf1 = *(const bf16x8*)(vb + (32 + col) * 128 + cb);
            o0 = __builtin_amdgcn_mfma_f32_32x32x16_bf16(pf, vf0, o0, 0, 0, 0);
            o1 = __builtin_amdgcn_mfma_f32_32x32x16_bf16(pf, vf1, o1, 0, 0, 0);
        }
        __builtin_amdgcn_s_setprio(0);

        __syncthreads();
        cur ^= 1;
    }

    li += __shfl_xor(li, 32);
    float inv = 1.0f / li;
#pragma unroll
    for (int reg = 0; reg < 16; ++reg) {
        const int crow = (reg & 3) + 8 * (reg >> 2) + 4 * h;
        float ivr = __shfl(inv, crow);
        const int row = qb + crow;
        u16* xp = Xa + ((size_t)b * 2048 + row) * 1024 + hd * 64;
        xp[col] = f2b(o0[reg] * ivr);
        xp[32 + col] = f2b(o1[reg] * ivr);
    }
}

// ---------------- launch --------------------------------------------------------
extern "C" void kernel_launch(void* const* d_in, const int* in_sizes, int n_in,
                              void* d_out, int out_size, void* d_ws, size_t ws_size,
                              hipStream_t stream) {
    const float* q   = (const float*)d_in[0];
    const float* k   = (const float*)d_in[1];
    const float* v   = (const float*)d_in[2];
    const float* Wq  = (const float*)d_in[3];
    const float* Wk  = (const float*)d_in[4];
    const float* Wv  = (const float*)d_in[5];
    const float* Wo  = (const float*)d_in[6];
    const float* bo  = (const float*)d_in[7];
    const float* qg  = (const float*)d_in[8];
    const float* qbt = (const float*)d_in[9];
    const float* kg  = (const float*)d_in[10];
    const float* kbt = (const float*)d_in[11];

    char* ws = (char*)d_ws;
    const float MUL_Q = 0.04508422002778f;   // (1/32) * log2(e)

    if (ws_size >= 109051904ULL) {
        // fused layout (104 MiB): Wt | Qa | Ka | Vt | Pb3 (3 slots)
        u16* Wt  = (u16*)(ws);                    //   0 ..  8 MiB
        u16* Qa  = (u16*)(ws + 8388608);          //  8 .. 24 MiB
        u16* Ka  = (u16*)(ws + 25165824);         // 24 .. 40 MiB
        u16* Vt  = (u16*)(ws + 41943040);         // 40 .. 56 MiB
        u16* Pb3 = (u16*)(ws + 58720256);         // 56 ..104 MiB
        u16* Xa  = Pb3;                           // Pb3 dead after ln2/vt

        wt_kernel<<<dim3(16, 16, 4), 256, 0, stream>>>(Wq, Wk, Wv, Wo, Wt);
        gemm3_kernel<<<1536, 256, 0, stream>>>(q, k, v, Wt, Pb3);
        ln2_kernel<<<dim3(8192, 1, 2), 256, 0, stream>>>(Pb3, qg, qbt, kg, kbt, Qa, Ka, MUL_Q);
        vt_kernel<<<dim3(32, 64), 256, 0, stream>>>(Pb3 + 2 * 8388608, Vt);
        attn_kernel<<<1024, 256, 0, stream>>>(Qa, Ka, Vt, Xa);
        gemm_kernel_f<<<512, 256, 0, stream>>>((const u16*)Xa, Wt + 3145728, (float*)d_out, bo);
    } else {
        // fallback serial layout (72 MiB): Wt | Pb | Qa | Ka | Vt
        u16* Wt = (u16*)(ws);
        u16* Pb = (u16*)(ws + 8388608);
        u16* Qa = (u16*)(ws + 25165824);
        u16* Ka = (u16*)(ws + 41943040);
        u16* Vt = (u16*)(ws + 58720256);
        u16* Xa = Pb;

        wt_kernel<<<dim3(16, 16, 4), 256, 0, stream>>>(Wq, Wk, Wv, Wo, Wt);
        gemm1_kernel<<<512, 256, 0, stream>>>(q, Wt, Pb);
        ln_kernel<<<8192, 256, 0, stream>>>(Pb, qg, qbt, MUL_Q, Qa);
        gemm1_kernel<<<512, 256, 0, stream>>>(k, Wt + 1048576, Pb);
        ln_kernel<<<8192, 256, 0, stream>>>(Pb, kg, kbt, 1.0f, Ka);
        gemm1_kernel<<<512, 256, 0, stream>>>(v, Wt + 2097152, Pb);
        vt_kernel<<<dim3(32, 64), 256, 0, stream>>>(Pb, Vt);
        attn_kernel<<<1024, 256, 0, stream>>>(Qa, Ka, Vt, Xa);
        gemm_kernel_f<<<512, 256, 0, stream>>>((const u16*)Xa, Wt + 3145728, (float*)d_out, bo);
    }
}